// Round 2
// baseline (23396.538 us; speedup 1.0000x reference)
//
#include <hip/hip_runtime.h>
#include <cmath>
#include <cstdint>
#include <cstddef>

#define B_ 8
#define N_ 2048
#define NT 2049
#define C_ 512
#define H_ 8
#define HD_ 64
#define L_ 8
#define M_ 128
#define HID_ 2048
#define NC_ 2
#define BNT (B_*NT)            /* 16392 */
#define SCALE_ 0.125f
#define LN_EPS_ 1e-5f
#define FEAT_EPS_ 1e-6f

#define MODE_SCALE 1
#define MODE_MASK  2
#define MODE_GELU  3
#define MODE_RESID 4

// ---------------- workspace layout (floats), total ~162.7 MB ----------------
constexpr size_t SZ_XACT = (size_t)BNT * C_;               // 8,392,704
constexpr size_t OFF_X   = 0;
constexpr size_t OFF_Q   = OFF_X + SZ_XACT;
constexpr size_t OFF_K   = OFF_Q + SZ_XACT;
constexpr size_t OFF_V   = OFF_K + SZ_XACT;
constexpr size_t OFF_KVP = OFF_V + SZ_XACT;                // 16*64*8192 = 8,388,608
constexpr size_t OFF_KSP = OFF_KVP + (size_t)16*64*8192;   // 131,072
constexpr size_t OFF_KV  = OFF_KSP + (size_t)16*64*128;    // 524,288
constexpr size_t OFF_KS  = OFF_KV + (size_t)64*M_*HD_;     // 8,192
constexpr size_t OFF_MU  = OFF_KS + (size_t)64*M_;         // 16,400 (padded)
constexpr size_t OFF_RS  = OFF_MU + 16400;
constexpr size_t WS_FLOATS = OFF_RS + 16400;               // 42,655,776 floats

// ---------------- helpers ----------------
__device__ __forceinline__ float wave_reduce(float v) {
#pragma unroll
  for (int off = 32; off > 0; off >>= 1) v += __shfl_down(v, off, 64);
  return v;
}

// ---------------- embedding ----------------
__global__ __launch_bounds__(256) void embed_k(const int* __restrict__ ids,
    const float* __restrict__ tok, const float* __restrict__ cls,
    const float* __restrict__ pos, float* __restrict__ X) {
  int row = blockIdx.x;
  int b = row / NT, n = row - b * NT;
  int t = threadIdx.x;
  const float* src = (n == 0) ? cls : tok + (size_t)ids[b * N_ + n - 1] * C_;
  X[(size_t)row * C_ + t]       = src[t]       + pos[(size_t)n * C_ + t];
  X[(size_t)row * C_ + t + 256] = src[t + 256] + pos[(size_t)n * C_ + t + 256];
}

// ---------------- LN stats: per-row mean + rsqrt(var+eps) ----------------
__global__ __launch_bounds__(256) void lnstat_k(const float* __restrict__ X,
    float* __restrict__ MU, float* __restrict__ RS) {
  int w = threadIdx.x >> 6, lane = threadIdx.x & 63;
  int row = blockIdx.x * 4 + w;
  if (row >= BNT) return;
  const float* xr = X + (size_t)row * C_;
  float v[8];
#pragma unroll
  for (int j = 0; j < 8; ++j) v[j] = xr[lane + j * 64];
  float s = 0.f;
#pragma unroll
  for (int j = 0; j < 8; ++j) s += v[j];
  s = wave_reduce(s);
  float mu = __shfl(s, 0, 64) * (1.0f / C_);
  float sq = 0.f;
#pragma unroll
  for (int j = 0; j < 8; ++j) { float d = v[j] - mu; sq = fmaf(d, d, sq); }
  sq = wave_reduce(sq);
  float var = __shfl(sq, 0, 64) * (1.0f / C_);
  if (lane == 0) { MU[row] = mu; RS[row] = rsqrtf(var + LN_EPS_); }
}

// ---------------- generic GEMM: C = epilogue(lnA(A)[MxK] @ W[KxN] + bias) ----------------
// 128x128 tile, 256 threads, 8x8 per thread, BK=16. Optional fused LayerNorm on A.
__global__ __launch_bounds__(256) void gemm_k(
    const float* __restrict__ A, int lda,
    const float* __restrict__ W, int ldw,
    const float* __restrict__ bias,
    float* __restrict__ Cmat, int ldc,
    int Mrows, int Kdim, int mode,
    const int* __restrict__ attn,
    const float* __restrict__ lnmu, const float* __restrict__ lnrs,
    const float* __restrict__ lng, const float* __restrict__ lnb) {
  __shared__ __align__(16) float As[16][132];
  __shared__ __align__(16) float Ws[16][132];
  const int t = threadIdx.x;
  const int row0 = blockIdx.y * 128;
  const int col0 = blockIdx.x * 128;
  const int tx = t & 15, ty = t >> 4;
  const int la_k = t & 15, la_r = t >> 4;
  const int lw_n = t & 127, lw_k = t >> 7;
  float acc[8][8] = {};
  float mu8[8], rs8[8];
  if (lnmu) {
#pragma unroll
    for (int p = 0; p < 8; ++p) {
      int grow = row0 + la_r + p * 16;
      mu8[p] = (grow < Mrows) ? lnmu[grow] : 0.f;
      rs8[p] = (grow < Mrows) ? lnrs[grow] : 0.f;
    }
  }
  for (int k0 = 0; k0 < Kdim; k0 += 16) {
    float gk = 0.f, bk = 0.f;
    if (lnmu) { gk = lng[k0 + la_k]; bk = lnb[k0 + la_k]; }
#pragma unroll
    for (int p = 0; p < 8; ++p) {
      int r = la_r + p * 16;
      int grow = row0 + r;
      float v = (grow < Mrows) ? A[(size_t)grow * lda + k0 + la_k] : 0.f;
      if (lnmu) v = (v - mu8[p]) * rs8[p] * gk + bk;
      As[la_k][r] = v;
    }
#pragma unroll
    for (int p = 0; p < 8; ++p) {
      int kk = lw_k + p * 2;
      Ws[kk][lw_n] = W[(size_t)(k0 + kk) * ldw + col0 + lw_n];
    }
    __syncthreads();
#pragma unroll
    for (int kk = 0; kk < 16; ++kk) {
      float a[8], w[8];
      *(float4*)&a[0] = *(const float4*)&As[kk][ty * 8];
      *(float4*)&a[4] = *(const float4*)&As[kk][ty * 8 + 4];
      *(float4*)&w[0] = *(const float4*)&Ws[kk][tx * 8];
      *(float4*)&w[4] = *(const float4*)&Ws[kk][tx * 8 + 4];
#pragma unroll
      for (int r = 0; r < 8; ++r)
#pragma unroll
        for (int c = 0; c < 8; ++c)
          acc[r][c] = fmaf(a[r], w[c], acc[r][c]);
    }
    __syncthreads();
  }
#pragma unroll
  for (int r = 0; r < 8; ++r) {
    int grow = row0 + ty * 8 + r;
    if (grow >= Mrows) continue;
    float mul = 1.f;
    if (mode == MODE_SCALE) mul = SCALE_;
    else if (mode == MODE_MASK) {
      int bb = grow / NT, nn = grow - bb * NT;
      mul = (nn == 0) ? 1.f : (float)attn[bb * N_ + nn - 1];
    }
    float* orow = Cmat + (size_t)grow * ldc + col0 + tx * 8;
    const float* brow = bias + col0 + tx * 8;
#pragma unroll
    for (int c = 0; c < 8; ++c) {
      float v = acc[r][c] + brow[c];
      if (mode == MODE_SCALE || mode == MODE_MASK) v *= mul;
      else if (mode == MODE_GELU) v = 0.5f * v * (1.f + erff(v * 0.70710678118654752f));
      else if (mode == MODE_RESID) v += orow[c];
      orow[c] = v;
    }
  }
}

// ---------------- kv partial with fused feature map ----------------
// per (chunk, b, h): kv[m][d] = sum_n kf[n][m]*v[n][d], ksum[m] = sum_n kf[n][m]
__global__ __launch_bounds__(256) void kvpart_k(const float* __restrict__ Kin,
    const float* __restrict__ Vin, const float* __restrict__ projL,
    float* __restrict__ KVP, float* __restrict__ KSP) {
  int ci = blockIdx.x, bh = blockIdx.y;
  int b = bh >> 3, h = bh & 7;
  int n0 = ci * 129;
  int n1 = min(n0 + 129, NT);
  __shared__ __align__(16) float Ps[64 * 132];
  __shared__ __align__(16) float kraw[8 * 68];
  __shared__ __align__(16) float kfs[8 * 132];
  __shared__ __align__(16) float vsm[8 * 68];
  int t = threadIdx.x;
  const float* ph = projL + (size_t)h * HD_ * M_;
#pragma unroll
  for (int p = 0; p < 32; ++p) {
    int e = p * 256 + t; int m = e & 127; int kk = e >> 7;
    Ps[kk * 132 + m] = ph[kk * 128 + m];
  }
  const int fm0 = (t & 31) * 4, ftok = t >> 5;       // feature mapping
  const int d0 = (t & 7) * 8, m0 = (t >> 3) * 4;     // accum mapping
  float acc[4][8] = {};
  float ks[4] = {};
  __syncthreads();
  for (int nb = n0; nb < n1; nb += 8) {
#pragma unroll
    for (int p = 0; p < 2; ++p) {
      int e = p * 256 + t; int d = e & 63; int tok = e >> 6;
      int n = nb + tok;
      bool ok = (n < n1);
      kraw[tok * 68 + d] = ok ? Kin[((size_t)b * NT + n) * C_ + h * HD_ + d] : 0.f;
      vsm [tok * 68 + d] = ok ? Vin[((size_t)b * NT + n) * C_ + h * HD_ + d] : 0.f;
    }
    __syncthreads();
    {
      float fa[4] = {0.f, 0.f, 0.f, 0.f};
      float xs = 0.f;
#pragma unroll 16
      for (int d = 0; d < 64; ++d) {
        float a = kraw[ftok * 68 + d];
        xs = fmaf(a, a, xs);
        float4 pv = *(const float4*)&Ps[d * 132 + fm0];
        fa[0] = fmaf(a, pv.x, fa[0]); fa[1] = fmaf(a, pv.y, fa[1]);
        fa[2] = fmaf(a, pv.z, fa[2]); fa[3] = fmaf(a, pv.w, fa[3]);
      }
      xs *= 0.5f;
      bool valid = (nb + ftok) < n1;
#pragma unroll
      for (int c = 0; c < 4; ++c)
        kfs[ftok * 132 + fm0 + c] = valid ? (expf(fa[c] - xs) + FEAT_EPS_) : 0.f;
    }
    __syncthreads();
#pragma unroll
    for (int tok = 0; tok < 8; ++tok) {
      float kq[4], va[8];
      *(float4*)&kq[0] = *(const float4*)&kfs[tok * 132 + m0];
      *(float4*)&va[0] = *(const float4*)&vsm[tok * 68 + d0];
      *(float4*)&va[4] = *(const float4*)&vsm[tok * 68 + d0 + 4];
#pragma unroll
      for (int mi = 0; mi < 4; ++mi)
#pragma unroll
        for (int di = 0; di < 8; ++di)
          acc[mi][di] = fmaf(kq[mi], va[di], acc[mi][di]);
      if ((t & 7) == 0) { ks[0] += kq[0]; ks[1] += kq[1]; ks[2] += kq[2]; ks[3] += kq[3]; }
    }
    __syncthreads();
  }
  size_t base = ((size_t)ci * 64 + bh) * 8192;
#pragma unroll
  for (int mi = 0; mi < 4; ++mi)
#pragma unroll
    for (int di = 0; di < 8; ++di)
      KVP[base + (size_t)(m0 + mi) * 64 + d0 + di] = acc[mi][di];
  if ((t & 7) == 0) {
#pragma unroll
    for (int mi = 0; mi < 4; ++mi)
      KSP[((size_t)ci * 64 + bh) * 128 + m0 + mi] = ks[mi];
  }
}

__global__ __launch_bounds__(256) void kvred_k(const float* __restrict__ KVP,
    const float* __restrict__ KSP, float* __restrict__ KV,
    float* __restrict__ KSUM) {
  int bh = blockIdx.x, t = threadIdx.x;
#pragma unroll
  for (int p = 0; p < 32; ++p) {
    int e = p * 256 + t;
    float s = 0.f;
#pragma unroll
    for (int ci = 0; ci < 16; ++ci) s += KVP[((size_t)ci * 64 + bh) * 8192 + e];
    KV[(size_t)bh * 8192 + e] = s;
  }
  if (t < 128) {
    float s = 0.f;
#pragma unroll
    for (int ci = 0; ci < 16; ++ci) s += KSP[((size_t)ci * 64 + bh) * 128 + t];
    KSUM[(size_t)bh * 128 + t] = s;
  }
}

// ---------------- ctx with fused feature map ----------------
// 32 tokens per block, one (b,h) per blockIdx.y. Single 61KB smem, phase-overlaid.
#define CTX_QR 0            /* qraw 32x68 = 2176 */
#define CTX_PS 2176         /* Ps 64x132 = 8448  */
#define CTX_XS 10624        /* xsq 32 */
#define CTX_QF 10656        /* qf 128x36 = 4608 -> end 15264 */
#define CTX_KVS 0           /* phase2: kv 128x68 = 8704 */
#define CTX_KSU 8704        /* ksum 128 */
#define CTX_DLS 8832        /* dls 32 */
#define CTX_DP  8864        /* dpart 8x32 = 256 -> end 9120 < 10656 */
#define CTX_SM  15264
__global__ __launch_bounds__(256) void ctx_k(const float* __restrict__ Qin,
    const float* __restrict__ projL, const float* __restrict__ KVg,
    const float* __restrict__ KSUM, float* __restrict__ CTX) {
  __shared__ __align__(16) float sm[CTX_SM];
  int t = threadIdx.x;
  int bh = blockIdx.y; int b = bh >> 3, h = bh & 7;
  int n00 = blockIdx.x * 32;
  const float* ph = projL + (size_t)h * HD_ * M_;
#pragma unroll
  for (int p = 0; p < 8; ++p) {
    int e = p * 256 + t; int d = e & 63; int r = e >> 6;
    int n = n00 + r;
    sm[CTX_QR + r * 68 + d] = (n < NT) ? Qin[((size_t)b * NT + n) * C_ + h * HD_ + d] : 0.f;
  }
#pragma unroll
  for (int p = 0; p < 32; ++p) {
    int e = p * 256 + t; int m = e & 127; int kk = e >> 7;
    sm[CTX_PS + kk * 132 + m] = ph[kk * 128 + m];
  }
  __syncthreads();
  if (t < 32) {
    float s = 0.f;
#pragma unroll 16
    for (int d = 0; d < 64; ++d) { float a = sm[CTX_QR + t * 68 + d]; s = fmaf(a, a, s); }
    sm[CTX_XS + t] = 0.5f * s;
  }
  __syncthreads();
  // features: thread computes 4 tokens x 4 m
  {
    const int m0 = (t & 31) * 4, tokg = t >> 5;
    float fa[4][4] = {};
#pragma unroll 8
    for (int d = 0; d < 64; ++d) {
      float4 pv = *(const float4*)&sm[CTX_PS + d * 132 + m0];
#pragma unroll
      for (int j = 0; j < 4; ++j) {
        float a = sm[CTX_QR + (tokg * 4 + j) * 68 + d];
        fa[j][0] = fmaf(a, pv.x, fa[j][0]); fa[j][1] = fmaf(a, pv.y, fa[j][1]);
        fa[j][2] = fmaf(a, pv.z, fa[j][2]); fa[j][3] = fmaf(a, pv.w, fa[j][3]);
      }
    }
    __syncthreads();  // qraw/Ps reads done; safe to overwrite below after feature store
#pragma unroll
    for (int j = 0; j < 4; ++j) {
      int tok = tokg * 4 + j;
      float xs = sm[CTX_XS + tok];
      bool valid = (n00 + tok) < NT;
#pragma unroll
      for (int c = 0; c < 4; ++c)
        sm[CTX_QF + (m0 + c) * 36 + tok] = valid ? (expf(fa[j][c] - xs) + FEAT_EPS_) : 0.f;
    }
  }
  __syncthreads();
  // phase2 loads (overlay qraw/Ps region)
#pragma unroll
  for (int p = 0; p < 32; ++p) {
    int e = p * 256 + t; int d = e & 63; int m = e >> 6;
    sm[CTX_KVS + m * 68 + d] = KVg[(size_t)bh * 8192 + e];
  }
  if (t < 128) sm[CTX_KSU + t] = KSUM[(size_t)bh * 128 + t];
  __syncthreads();
  // denominator
  {
    int j = t & 31, pp = t >> 5;
    float s = 0.f;
#pragma unroll
    for (int mi = 0; mi < 16; ++mi) {
      int m = pp * 16 + mi;
      s = fmaf(sm[CTX_QF + m * 36 + j], sm[CTX_KSU + m], s);
    }
    sm[CTX_DP + pp * 32 + j] = s;
  }
  __syncthreads();
  if (t < 32) {
    float den = 0.f;
#pragma unroll
    for (int pp = 0; pp < 8; ++pp) den += sm[CTX_DP + pp * 32 + t];
    sm[CTX_DLS + t] = 1.f / fmaxf(den, 1e-6f);
  }
  __syncthreads();
  // numerator: thread computes 2 tokens x 4 d
  {
    const int d0 = (t & 15) * 4, tok0 = (t >> 4) * 2;
    float acc[2][4] = {};
#pragma unroll 16
    for (int m = 0; m < 128; ++m) {
      float q0 = sm[CTX_QF + m * 36 + tok0];
      float q1 = sm[CTX_QF + m * 36 + tok0 + 1];
      float4 kv4 = *(const float4*)&sm[CTX_KVS + m * 68 + d0];
      acc[0][0] = fmaf(q0, kv4.x, acc[0][0]); acc[0][1] = fmaf(q0, kv4.y, acc[0][1]);
      acc[0][2] = fmaf(q0, kv4.z, acc[0][2]); acc[0][3] = fmaf(q0, kv4.w, acc[0][3]);
      acc[1][0] = fmaf(q1, kv4.x, acc[1][0]); acc[1][1] = fmaf(q1, kv4.y, acc[1][1]);
      acc[1][2] = fmaf(q1, kv4.z, acc[1][2]); acc[1][3] = fmaf(q1, kv4.w, acc[1][3]);
    }
#pragma unroll
    for (int r = 0; r < 2; ++r) {
      int n = n00 + tok0 + r;
      if (n >= NT) continue;
      float rd = sm[CTX_DLS + tok0 + r];
      float* o = CTX + ((size_t)b * NT + n) * C_ + h * HD_ + d0;
#pragma unroll
      for (int c = 0; c < 4; ++c) o[c] = acc[r][c] * rd;
    }
  }
}

// ---------------- final: LN(x[b,0]) @ headW + headb ----------------
__global__ __launch_bounds__(256) void final_k(const float* __restrict__ X,
    const float* __restrict__ g, const float* __restrict__ beta,
    const float* __restrict__ hW, const float* __restrict__ hb,
    float* __restrict__ out) {
  int b = blockIdx.x, t = threadIdx.x;
  const float* xr = X + (size_t)b * NT * C_;
  float v0 = xr[t], v1 = xr[t + 256];
  __shared__ float red[4][4];
  float s = wave_reduce(v0 + v1);
  if ((t & 63) == 0) red[0][t >> 6] = s;
  __syncthreads();
  float mu = (red[0][0] + red[0][1] + red[0][2] + red[0][3]) * (1.0f / C_);
  float d0 = v0 - mu, d1 = v1 - mu;
  float s2 = wave_reduce(d0 * d0 + d1 * d1);
  if ((t & 63) == 0) red[1][t >> 6] = s2;
  __syncthreads();
  float var = (red[1][0] + red[1][1] + red[1][2] + red[1][3]) * (1.0f / C_);
  float rs = rsqrtf(var + LN_EPS_);
  float n0 = d0 * rs * g[t] + beta[t];
  float n1 = d1 * rs * g[t + 256] + beta[t + 256];
  float p0 = n0 * hW[t * NC_]     + n1 * hW[(t + 256) * NC_];
  float p1 = n0 * hW[t * NC_ + 1] + n1 * hW[(t + 256) * NC_ + 1];
  float t0 = wave_reduce(p0);
  float t1 = wave_reduce(p1);
  if ((t & 63) == 0) { red[2][t >> 6] = t0; red[3][t >> 6] = t1; }
  __syncthreads();
  if (t == 0) {
    out[b * NC_]     = red[2][0] + red[2][1] + red[2][2] + red[2][3] + hb[0];
    out[b * NC_ + 1] = red[3][0] + red[3][1] + red[3][2] + red[3][3] + hb[1];
  }
}

// ---------------- launch ----------------
extern "C" void kernel_launch(void* const* d_in, const int* in_sizes, int n_in,
                              void* d_out, int out_size, void* d_ws, size_t ws_size,
                              hipStream_t stream) {
  if (ws_size < WS_FLOATS * sizeof(float)) return;  // diagnostic: absmax-fail instead of fault
  const int*   ids   = (const int*)d_in[0];
  const int*   attn  = (const int*)d_in[1];
  const float* tok   = (const float*)d_in[2];
  const float* cls   = (const float*)d_in[3];
  const float* pos   = (const float*)d_in[4];
  const float* ln1g  = (const float*)d_in[5];
  const float* ln1b  = (const float*)d_in[6];
  const float* qW    = (const float*)d_in[7];
  const float* qb    = (const float*)d_in[8];
  const float* kW    = (const float*)d_in[9];
  const float* kb    = (const float*)d_in[10];
  const float* vW    = (const float*)d_in[11];
  const float* vb    = (const float*)d_in[12];
  const float* oW    = (const float*)d_in[13];
  const float* ob    = (const float*)d_in[14];
  const float* proj  = (const float*)d_in[15];
  const float* ln2g  = (const float*)d_in[16];
  const float* ln2b  = (const float*)d_in[17];
  const float* fc1W  = (const float*)d_in[18];
  const float* fc1b  = (const float*)d_in[19];
  const float* fc2W  = (const float*)d_in[20];
  const float* fc2b  = (const float*)d_in[21];
  const float* lnfg  = (const float*)d_in[22];
  const float* lnfb  = (const float*)d_in[23];
  const float* headW = (const float*)d_in[24];
  const float* headb = (const float*)d_in[25];

  float* ws   = (float*)d_ws;
  float* X    = ws + OFF_X;
  float* Q    = ws + OFF_Q;
  float* Kb_  = ws + OFF_K;
  float* Vb_  = ws + OFF_V;
  float* KVP  = ws + OFF_KVP;
  float* KSP  = ws + OFF_KSP;
  float* KV   = ws + OFF_KV;
  float* KSUM = ws + OFF_KS;
  float* MU   = ws + OFF_MU;
  float* RS   = ws + OFF_RS;
  float* CTX  = Vb_;   // V dead after kvpart
  float* HB   = Q;     // Q..K span = 16,785,408 floats = 8196*2048 exactly

  embed_k<<<BNT, 256, 0, stream>>>(ids, tok, cls, pos, X);
  for (int i = 0; i < L_; ++i) {
    const float* pj = proj + (size_t)i * H_ * HD_ * M_;
    lnstat_k<<<(BNT + 3) / 4, 256, 0, stream>>>(X, MU, RS);
    gemm_k<<<dim3(4, 129), 256, 0, stream>>>(X, C_, qW + (size_t)i * C_ * C_, C_,
        qb + i * C_, Q, C_, BNT, C_, MODE_SCALE, attn, MU, RS, ln1g + i * C_, ln1b + i * C_);
    gemm_k<<<dim3(4, 129), 256, 0, stream>>>(X, C_, kW + (size_t)i * C_ * C_, C_,
        kb + i * C_, Kb_, C_, BNT, C_, MODE_MASK, attn, MU, RS, ln1g + i * C_, ln1b + i * C_);
    gemm_k<<<dim3(4, 129), 256, 0, stream>>>(X, C_, vW + (size_t)i * C_ * C_, C_,
        vb + i * C_, Vb_, C_, BNT, C_, MODE_MASK, attn, MU, RS, ln1g + i * C_, ln1b + i * C_);
    kvpart_k<<<dim3(16, 64), 256, 0, stream>>>(Kb_, Vb_, pj, KVP, KSP);
    kvred_k<<<64, 256, 0, stream>>>(KVP, KSP, KV, KSUM);
    ctx_k<<<dim3(65, 64), 256, 0, stream>>>(Q, pj, KV, KSUM, CTX);
    gemm_k<<<dim3(4, 129), 256, 0, stream>>>(CTX, C_, oW + (size_t)i * C_ * C_, C_,
        ob + i * C_, X, C_, BNT, C_, MODE_RESID, attn, nullptr, nullptr, nullptr, nullptr);
    lnstat_k<<<(BNT + 3) / 4, 256, 0, stream>>>(X, MU, RS);
    for (int c2 = 0; c2 < 2; ++c2) {
      size_t off = (size_t)c2 * 8196;
      gemm_k<<<dim3(16, 65), 256, 0, stream>>>(X + off * C_, C_,
          fc1W + (size_t)i * C_ * HID_, HID_, fc1b + i * HID_, HB, HID_,
          8196, C_, MODE_GELU, attn, MU + off, RS + off, ln2g + i * C_, ln2b + i * C_);
      gemm_k<<<dim3(4, 65), 256, 0, stream>>>(HB, HID_,
          fc2W + (size_t)i * HID_ * C_, C_, fc2b + i * C_, X + off * C_, C_,
          8196, HID_, MODE_RESID, attn, nullptr, nullptr, nullptr, nullptr);
    }
  }
  final_k<<<B_, 256, 0, stream>>>(X, lnfg, lnfb, headW, headb, (float*)d_out);
}

// Round 3
// 5437.178 us; speedup vs baseline: 4.3031x; 4.3031x over previous
//
#include <hip/hip_runtime.h>
#include <cmath>
#include <cstdint>
#include <cstddef>

#define B_ 8
#define N_ 2048
#define NT 2049
#define C_ 512
#define H_ 8
#define HD_ 64
#define L_ 8
#define M_ 128
#define HID_ 2048
#define NC_ 2
#define BNT (B_*NT)            /* 16392 */
#define MPAD 16512             /* 129*128 padded rows */
#define SCALE_ 0.125f
#define LN_EPS_ 1e-5f
#define FEAT_EPS_ 1e-6f

#define MODE_QKV   1
#define MODE_GELU  2
#define MODE_RESID 3

typedef unsigned short u16;
typedef unsigned short u16x8 __attribute__((ext_vector_type(8)));
typedef short frag __attribute__((ext_vector_type(8)));
typedef float f32x4 __attribute__((ext_vector_type(4)));

// ---------------- workspace layout ----------------
// floats
constexpr size_t F_X    = 0;                        // MPAD*512 = 8,454,144
constexpr size_t F_KVP  = F_X   + (size_t)MPAD*512; // 8*64*8192 = 4,194,304
constexpr size_t F_KSP  = F_KVP + (size_t)8*64*8192;  // 65,536
constexpr size_t F_KV   = F_KSP + (size_t)8*64*128;   // 524,288
constexpr size_t F_KS   = F_KV  + (size_t)64*M_*HD_;  // 8,192
constexpr size_t F_QKVB = F_KS  + (size_t)64*M_;      // 1536
constexpr size_t F_END  = F_QKVB + 1536;              // 13,248,000 floats
// ushorts, offset from (u16*)ws + 2*F_END
constexpr size_t S_BASE = 2 * F_END;
constexpr size_t S_Y    = S_BASE;                       // MPAD*512
constexpr size_t S_QKV  = S_Y    + (size_t)MPAD*512;    // MPAD*1536
constexpr size_t S_HB   = S_QKV  + (size_t)MPAD*1536;   // 8320*2048
constexpr size_t S_WQKV = S_HB   + (size_t)8320*2048;   // 1536*512
constexpr size_t S_WO   = S_WQKV + (size_t)1536*512;    // 512*512
constexpr size_t S_WF1  = S_WO   + (size_t)512*512;     // 2048*512
constexpr size_t S_WF2  = S_WF1  + (size_t)2048*512;    // 512*2048
constexpr size_t S_END  = S_WF2  + (size_t)512*2048;
constexpr size_t WS_BYTES = S_END * 2;                  // 160,995,328

// ---------------- helpers ----------------
__device__ __forceinline__ float wave_reduce(float v) {
#pragma unroll
  for (int off = 32; off > 0; off >>= 1) v += __shfl_down(v, off, 64);
  return v;
}
__device__ __forceinline__ float b2f(u16 u) {
  union { float f; uint32_t i; } v; v.i = ((uint32_t)u) << 16; return v.f;
}
__device__ __forceinline__ u16 f2b(float f) {
  union { float f; uint32_t i; } v; v.f = f;
  uint32_t r = v.i + 0x7FFF + ((v.i >> 16) & 1);
  return (u16)(r >> 16);
}

// ---------------- embedding ----------------
__global__ __launch_bounds__(256) void embed_k(const int* __restrict__ ids,
    const float* __restrict__ tok, const float* __restrict__ cls,
    const float* __restrict__ pos, float* __restrict__ X) {
  int row = blockIdx.x;
  int b = row / NT, n = row - b * NT;
  int t = threadIdx.x;
  const float* src = (n == 0) ? cls : tok + (size_t)ids[b * N_ + n - 1] * C_;
  X[(size_t)row * C_ + t]       = src[t]       + pos[(size_t)n * C_ + t];
  X[(size_t)row * C_ + t + 256] = src[t + 256] + pos[(size_t)n * C_ + t + 256];
}

// ---------------- weight transpose + fp32->bf16 convert (per layer) ----------------
// dst layouts are W^T: [n][k], k contiguous.
__global__ __launch_bounds__(256) void wconv_k(
    const float* __restrict__ qW, const float* __restrict__ kW,
    const float* __restrict__ vW, const float* __restrict__ oW,
    const float* __restrict__ f1W, const float* __restrict__ f2W,
    u16* __restrict__ Wqkv, u16* __restrict__ Wo,
    u16* __restrict__ Wf1, u16* __restrict__ Wf2) {
  __shared__ float tile[32][33];
  int bid = blockIdx.x, t = threadIdx.x;
  int ti = t >> 5, tj = t & 31;
  const float* src; u16* dst; int k0, n0, ldn, ldk, scol;
  if (bid < 768) {                       // qkv: 16 k-tiles x 48 n-tiles
    int tk = bid & 15, tn = bid >> 4;
    k0 = tk * 32; n0 = tn * 32;
    int sel = n0 >> 9; scol = n0 & 511;
    src = (sel == 0) ? qW : (sel == 1) ? kW : vW;
    ldn = 512; dst = Wqkv; ldk = 512;
  } else if (bid < 1024) {               // o: 16 x 16
    int b2 = bid - 768;
    int tk = b2 & 15, tn = b2 >> 4;
    k0 = tk * 32; n0 = tn * 32; scol = n0;
    src = oW; ldn = 512; dst = Wo; ldk = 512;
  } else if (bid < 2048) {               // fc1: src [512][2048], 16 k x 64 n
    int b2 = bid - 1024;
    int tk = b2 & 15, tn = b2 >> 4;
    k0 = tk * 32; n0 = tn * 32; scol = n0;
    src = f1W; ldn = 2048; dst = Wf1; ldk = 512;
  } else {                               // fc2: src [2048][512], 64 k x 16 n
    int b2 = bid - 2048;
    int tk = b2 & 63, tn = b2 >> 6;
    k0 = tk * 32; n0 = tn * 32; scol = n0;
    src = f2W; ldn = 512; dst = Wf2; ldk = 2048;
  }
  const float* sp = src + (size_t)k0 * ldn + scol;
  u16* dp = dst + (size_t)n0 * ldk + k0;
#pragma unroll
  for (int p = 0; p < 4; ++p)
    tile[ti + p * 8][tj] = sp[(size_t)(ti + p * 8) * ldn + tj];
  __syncthreads();
#pragma unroll
  for (int p = 0; p < 4; ++p)
    dp[(size_t)(ti + p * 8) * ldk + tj] = f2b(tile[tj][ti + p * 8]);
}

__global__ __launch_bounds__(256) void qkvb_k(const float* __restrict__ qb,
    const float* __restrict__ kb, const float* __restrict__ vb,
    float* __restrict__ QKVB) {
  int i = blockIdx.x * 256 + threadIdx.x;
  QKVB[i] = (i < 512) ? qb[i] : (i < 1024) ? kb[i - 512] : vb[i - 1024];
}

// ---------------- LayerNorm -> bf16 ----------------
__global__ __launch_bounds__(256) void ln_bf_k(const float* __restrict__ X,
    const float* __restrict__ g, const float* __restrict__ b,
    u16* __restrict__ Y) {
  int w = threadIdx.x >> 6, lane = threadIdx.x & 63;
  int row = blockIdx.x * 4 + w;
  const float* xr = X + (size_t)row * C_;
  float v[8];
  *(float4*)&v[0] = *(const float4*)(xr + lane * 8);
  *(float4*)&v[4] = *(const float4*)(xr + lane * 8 + 4);
  float s = 0.f;
#pragma unroll
  for (int j = 0; j < 8; ++j) s += v[j];
  s = wave_reduce(s);
  float mu = __shfl(s, 0, 64) * (1.0f / C_);
  float sq = 0.f;
#pragma unroll
  for (int j = 0; j < 8; ++j) { float d = v[j] - mu; sq = fmaf(d, d, sq); }
  sq = wave_reduce(sq);
  float rs = rsqrtf(__shfl(sq, 0, 64) * (1.0f / C_) + LN_EPS_);
  float gv[8], bv[8];
  *(float4*)&gv[0] = *(const float4*)(g + lane * 8);
  *(float4*)&gv[4] = *(const float4*)(g + lane * 8 + 4);
  *(float4*)&bv[0] = *(const float4*)(b + lane * 8);
  *(float4*)&bv[4] = *(const float4*)(b + lane * 8 + 4);
  u16x8 o;
#pragma unroll
  for (int j = 0; j < 8; ++j) o[j] = f2b((v[j] - mu) * rs * gv[j] + bv[j]);
  *(u16x8*)(Y + (size_t)row * C_ + lane * 8) = o;
}

// ---------------- bf16 MFMA GEMM ----------------
// C[MxN] = epi(A[Mx K] @ W^T[N x K]^T + bias). 128x128 tile, BK=32,
// 256 thr = 4 waves, each wave 64x64 via 4x4 of mfma 16x16x32.
__global__ __launch_bounds__(256) void gemm_bf_k(
    const u16* __restrict__ A, int lda,
    const u16* __restrict__ Wt,          // [N][Kdim] bf16
    const float* __restrict__ bias,
    float* __restrict__ outF, u16* __restrict__ outB,
    int ldc, int Kdim, int mode, const int* __restrict__ attn) {
  __shared__ __align__(16) u16 As[128 * 40];   // rows padded 32->40 shorts
  __shared__ __align__(16) u16 Bs[128 * 40];
  const int t = threadIdx.x;
  const int row0 = blockIdx.y * 128;
  const int col0 = blockIdx.x * 128;
  const int cr = t >> 2, cs = t & 3;           // staging: chunk row / k-seg
  const int w = t >> 6, l = t & 63;
  const int wm = w & 1, wn = w >> 1;
  const int lm = l & 15, lkb = l >> 4;
  const u16* Ag = A + (size_t)row0 * lda;
  const u16* Bg = Wt + (size_t)col0 * Kdim;
  f32x4 acc[4][4] = {};
  for (int k0 = 0; k0 < Kdim; k0 += 32) {
    u16x8 av0 = *(const u16x8*)(Ag + (size_t)cr * lda + k0 + cs * 8);
    u16x8 av1 = *(const u16x8*)(Ag + (size_t)(cr + 64) * lda + k0 + cs * 8);
    u16x8 bv0 = *(const u16x8*)(Bg + (size_t)cr * Kdim + k0 + cs * 8);
    u16x8 bv1 = *(const u16x8*)(Bg + (size_t)(cr + 64) * Kdim + k0 + cs * 8);
    __syncthreads();
    *(u16x8*)&As[cr * 40 + cs * 8] = av0;
    *(u16x8*)&As[(cr + 64) * 40 + cs * 8] = av1;
    *(u16x8*)&Bs[cr * 40 + cs * 8] = bv0;
    *(u16x8*)&Bs[(cr + 64) * 40 + cs * 8] = bv1;
    __syncthreads();
    frag af[4], bf[4];
#pragma unroll
    for (int i = 0; i < 4; ++i)
      af[i] = *(const frag*)&As[(wm * 64 + i * 16 + lm) * 40 + lkb * 8];
#pragma unroll
    for (int j = 0; j < 4; ++j)
      bf[j] = *(const frag*)&Bs[(wn * 64 + j * 16 + lm) * 40 + lkb * 8];
#pragma unroll
    for (int i = 0; i < 4; ++i)
#pragma unroll
      for (int j = 0; j < 4; ++j)
        acc[i][j] = __builtin_amdgcn_mfma_f32_16x16x32_bf16(af[i], bf[j], acc[i][j], 0, 0, 0);
  }
  // epilogue: lane holds rows (lkb*4+r), col lm of each 16x16 tile
#pragma unroll
  for (int i = 0; i < 4; ++i) {
#pragma unroll
    for (int j = 0; j < 4; ++j) {
      int gcol = col0 + wn * 64 + j * 16 + lm;
      float bia = bias[gcol];
#pragma unroll
      for (int r = 0; r < 4; ++r) {
        int grow = row0 + wm * 64 + i * 16 + lkb * 4 + r;
        float v = acc[i][j][r] + bia;
        if (mode == MODE_QKV) {
          if (gcol < 512) v *= SCALE_;
          else if (grow < BNT) {
            int bb = grow / NT, nn = grow - bb * NT;
            if (nn != 0) v *= (float)attn[bb * N_ + nn - 1];
          }
          outB[(size_t)grow * ldc + gcol] = f2b(v);
        } else if (mode == MODE_GELU) {
          v = 0.5f * v * (1.f + erff(v * 0.70710678118654752f));
          outB[(size_t)grow * ldc + gcol] = f2b(v);
        } else { // MODE_RESID
          outF[(size_t)grow * ldc + gcol] += v;
        }
      }
    }
  }
}

// ---------------- kv partial with fused feature map (bf16 inputs) ----------------
__global__ __launch_bounds__(256) void kvpart_k(const u16* __restrict__ Kin,
    const u16* __restrict__ Vin, const float* __restrict__ projL,
    float* __restrict__ KVP, float* __restrict__ KSP) {
  int ci = blockIdx.x, bh = blockIdx.y;
  int b = bh >> 3, h = bh & 7;
  int n0 = ci * 257;
  int n1 = min(n0 + 257, NT);
  __shared__ __align__(16) float Ps[64 * 132];
  __shared__ __align__(16) float kraw[8 * 68];
  __shared__ __align__(16) float kfs[8 * 132];
  __shared__ __align__(16) float vsm[8 * 68];
  int t = threadIdx.x;
  const float* ph = projL + (size_t)h * HD_ * M_;
#pragma unroll
  for (int p = 0; p < 32; ++p) {
    int e = p * 256 + t; int m = e & 127; int kk = e >> 7;
    Ps[kk * 132 + m] = ph[kk * 128 + m];
  }
  const int fm0 = (t & 31) * 4, ftok = t >> 5;
  const int d0 = (t & 7) * 8, m0 = (t >> 3) * 4;
  float acc[4][8] = {};
  float ks[4] = {};
  __syncthreads();
  for (int nb = n0; nb < n1; nb += 8) {
#pragma unroll
    for (int p = 0; p < 2; ++p) {
      int e = p * 256 + t; int d = e & 63; int tok = e >> 6;
      int n = nb + tok;
      bool ok = (n < n1);
      size_t base = ((size_t)b * NT + n) * 1536 + h * HD_ + d;
      kraw[tok * 68 + d] = ok ? b2f(Kin[base]) : 0.f;
      vsm [tok * 68 + d] = ok ? b2f(Vin[base]) : 0.f;
    }
    __syncthreads();
    {
      float fa[4] = {0.f, 0.f, 0.f, 0.f};
      float xs = 0.f;
#pragma unroll 16
      for (int d = 0; d < 64; ++d) {
        float a = kraw[ftok * 68 + d];
        xs = fmaf(a, a, xs);
        float4 pv = *(const float4*)&Ps[d * 132 + fm0];
        fa[0] = fmaf(a, pv.x, fa[0]); fa[1] = fmaf(a, pv.y, fa[1]);
        fa[2] = fmaf(a, pv.z, fa[2]); fa[3] = fmaf(a, pv.w, fa[3]);
      }
      xs *= 0.5f;
      bool valid = (nb + ftok) < n1;
#pragma unroll
      for (int c = 0; c < 4; ++c)
        kfs[ftok * 132 + fm0 + c] = valid ? (expf(fa[c] - xs) + FEAT_EPS_) : 0.f;
    }
    __syncthreads();
#pragma unroll
    for (int tok = 0; tok < 8; ++tok) {
      float kq[4], va[8];
      *(float4*)&kq[0] = *(const float4*)&kfs[tok * 132 + m0];
      *(float4*)&va[0] = *(const float4*)&vsm[tok * 68 + d0];
      *(float4*)&va[4] = *(const float4*)&vsm[tok * 68 + d0 + 4];
#pragma unroll
      for (int mi = 0; mi < 4; ++mi)
#pragma unroll
        for (int di = 0; di < 8; ++di)
          acc[mi][di] = fmaf(kq[mi], va[di], acc[mi][di]);
      if ((t & 7) == 0) { ks[0] += kq[0]; ks[1] += kq[1]; ks[2] += kq[2]; ks[3] += kq[3]; }
    }
    __syncthreads();
  }
  size_t base = ((size_t)ci * 64 + bh) * 8192;
#pragma unroll
  for (int mi = 0; mi < 4; ++mi)
#pragma unroll
    for (int di = 0; di < 8; ++di)
      KVP[base + (size_t)(m0 + mi) * 64 + d0 + di] = acc[mi][di];
  if ((t & 7) == 0) {
#pragma unroll
    for (int mi = 0; mi < 4; ++mi)
      KSP[((size_t)ci * 64 + bh) * 128 + m0 + mi] = ks[mi];
  }
}

__global__ __launch_bounds__(256) void kvred_k(const float* __restrict__ KVP,
    const float* __restrict__ KSP, float* __restrict__ KV,
    float* __restrict__ KSUM) {
  int bh = blockIdx.x, t = threadIdx.x;
#pragma unroll
  for (int p = 0; p < 32; ++p) {
    int e = p * 256 + t;
    float s = 0.f;
#pragma unroll
    for (int ci = 0; ci < 8; ++ci) s += KVP[((size_t)ci * 64 + bh) * 8192 + e];
    KV[(size_t)bh * 8192 + e] = s;
  }
  if (t < 128) {
    float s = 0.f;
#pragma unroll
    for (int ci = 0; ci < 8; ++ci) s += KSP[((size_t)ci * 64 + bh) * 128 + t];
    KSUM[(size_t)bh * 128 + t] = s;
  }
}

// ---------------- ctx with fused feature map (bf16 in/out) ----------------
#define CTX_QR 0
#define CTX_PS 2176
#define CTX_XS 10624
#define CTX_QF 10656
#define CTX_KVS 0
#define CTX_KSU 8704
#define CTX_DLS 8832
#define CTX_DP  8864
#define CTX_SM  15264
__global__ __launch_bounds__(256) void ctx_k(const u16* __restrict__ Qin,
    const float* __restrict__ projL, const float* __restrict__ KVg,
    const float* __restrict__ KSUM, u16* __restrict__ CTXo) {
  __shared__ __align__(16) float sm[CTX_SM];
  int t = threadIdx.x;
  int bh = blockIdx.y; int b = bh >> 3, h = bh & 7;
  int n00 = blockIdx.x * 32;
  const float* ph = projL + (size_t)h * HD_ * M_;
#pragma unroll
  for (int p = 0; p < 8; ++p) {
    int e = p * 256 + t; int d = e & 63; int r = e >> 6;
    int n = n00 + r;
    sm[CTX_QR + r * 68 + d] = (n < NT) ? b2f(Qin[((size_t)b * NT + n) * 1536 + h * HD_ + d]) : 0.f;
  }
#pragma unroll
  for (int p = 0; p < 32; ++p) {
    int e = p * 256 + t; int m = e & 127; int kk = e >> 7;
    sm[CTX_PS + kk * 132 + m] = ph[kk * 128 + m];
  }
  __syncthreads();
  if (t < 32) {
    float s = 0.f;
#pragma unroll 16
    for (int d = 0; d < 64; ++d) { float a = sm[CTX_QR + t * 68 + d]; s = fmaf(a, a, s); }
    sm[CTX_XS + t] = 0.5f * s;
  }
  __syncthreads();
  {
    const int m0 = (t & 31) * 4, tokg = t >> 5;
    float fa[4][4] = {};
#pragma unroll 8
    for (int d = 0; d < 64; ++d) {
      float4 pv = *(const float4*)&sm[CTX_PS + d * 132 + m0];
#pragma unroll
      for (int j = 0; j < 4; ++j) {
        float a = sm[CTX_QR + (tokg * 4 + j) * 68 + d];
        fa[j][0] = fmaf(a, pv.x, fa[j][0]); fa[j][1] = fmaf(a, pv.y, fa[j][1]);
        fa[j][2] = fmaf(a, pv.z, fa[j][2]); fa[j][3] = fmaf(a, pv.w, fa[j][3]);
      }
    }
    __syncthreads();
#pragma unroll
    for (int j = 0; j < 4; ++j) {
      int tok = tokg * 4 + j;
      float xs = sm[CTX_XS + tok];
      bool valid = (n00 + tok) < NT;
#pragma unroll
      for (int c = 0; c < 4; ++c)
        sm[CTX_QF + (m0 + c) * 36 + tok] = valid ? (expf(fa[j][c] - xs) + FEAT_EPS_) : 0.f;
    }
  }
  __syncthreads();
#pragma unroll
  for (int p = 0; p < 32; ++p) {
    int e = p * 256 + t; int d = e & 63; int m = e >> 6;
    sm[CTX_KVS + m * 68 + d] = KVg[(size_t)bh * 8192 + e];
  }
  if (t < 128) sm[CTX_KSU + t] = KSUM[(size_t)bh * 128 + t];
  __syncthreads();
  {
    int j = t & 31, pp = t >> 5;
    float s = 0.f;
#pragma unroll
    for (int mi = 0; mi < 16; ++mi) {
      int m = pp * 16 + mi;
      s = fmaf(sm[CTX_QF + m * 36 + j], sm[CTX_KSU + m], s);
    }
    sm[CTX_DP + pp * 32 + j] = s;
  }
  __syncthreads();
  if (t < 32) {
    float den = 0.f;
#pragma unroll
    for (int pp = 0; pp < 8; ++pp) den += sm[CTX_DP + pp * 32 + t];
    sm[CTX_DLS + t] = 1.f / fmaxf(den, 1e-6f);
  }
  __syncthreads();
  {
    const int d0 = (t & 15) * 4, tok0 = (t >> 4) * 2;
    float acc[2][4] = {};
#pragma unroll 16
    for (int m = 0; m < 128; ++m) {
      float q0 = sm[CTX_QF + m * 36 + tok0];
      float q1 = sm[CTX_QF + m * 36 + tok0 + 1];
      float4 kv4 = *(const float4*)&sm[CTX_KVS + m * 68 + d0];
      acc[0][0] = fmaf(q0, kv4.x, acc[0][0]); acc[0][1] = fmaf(q0, kv4.y, acc[0][1]);
      acc[0][2] = fmaf(q0, kv4.z, acc[0][2]); acc[0][3] = fmaf(q0, kv4.w, acc[0][3]);
      acc[1][0] = fmaf(q1, kv4.x, acc[1][0]); acc[1][1] = fmaf(q1, kv4.y, acc[1][1]);
      acc[1][2] = fmaf(q1, kv4.z, acc[1][2]); acc[1][3] = fmaf(q1, kv4.w, acc[1][3]);
    }
#pragma unroll
    for (int r = 0; r < 2; ++r) {
      int n = n00 + tok0 + r;
      if (n >= NT) continue;
      float rd = sm[CTX_DLS + tok0 + r];
      u16* o = CTXo + ((size_t)b * NT + n) * C_ + h * HD_ + d0;
#pragma unroll
      for (int c = 0; c < 4; ++c) o[c] = f2b(acc[r][c] * rd);
    }
  }
}

// ---------------- final: LN(x[b,0]) @ headW + headb ----------------
__global__ __launch_bounds__(256) void final_k(const float* __restrict__ X,
    const float* __restrict__ g, const float* __restrict__ beta,
    const float* __restrict__ hW, const float* __restrict__ hb,
    float* __restrict__ out) {
  int b = blockIdx.x, t = threadIdx.x;
  const float* xr = X + (size_t)b * NT * C_;
  float v0 = xr[t], v1 = xr[t + 256];
  __shared__ float red[4][4];
  float s = wave_reduce(v0 + v1);
  if ((t & 63) == 0) red[0][t >> 6] = s;
  __syncthreads();
  float mu = (red[0][0] + red[0][1] + red[0][2] + red[0][3]) * (1.0f / C_);
  float d0 = v0 - mu, d1 = v1 - mu;
  float s2 = wave_reduce(d0 * d0 + d1 * d1);
  if ((t & 63) == 0) red[1][t >> 6] = s2;
  __syncthreads();
  float var = (red[1][0] + red[1][1] + red[1][2] + red[1][3]) * (1.0f / C_);
  float rs = rsqrtf(var + LN_EPS_);
  float n0 = d0 * rs * g[t] + beta[t];
  float n1 = d1 * rs * g[t + 256] + beta[t + 256];
  float p0 = n0 * hW[t * NC_]     + n1 * hW[(t + 256) * NC_];
  float p1 = n0 * hW[t * NC_ + 1] + n1 * hW[(t + 256) * NC_ + 1];
  float t0 = wave_reduce(p0);
  float t1 = wave_reduce(p1);
  if ((t & 63) == 0) { red[2][t >> 6] = t0; red[3][t >> 6] = t1; }
  __syncthreads();
  if (t == 0) {
    out[b * NC_]     = red[2][0] + red[2][1] + red[2][2] + red[2][3] + hb[0];
    out[b * NC_ + 1] = red[3][0] + red[3][1] + red[3][2] + red[3][3] + hb[1];
  }
}

// ---------------- launch ----------------
extern "C" void kernel_launch(void* const* d_in, const int* in_sizes, int n_in,
                              void* d_out, int out_size, void* d_ws, size_t ws_size,
                              hipStream_t stream) {
  if (ws_size < WS_BYTES) return;  // diagnostic guard
  const int*   ids   = (const int*)d_in[0];
  const int*   attn  = (const int*)d_in[1];
  const float* tok   = (const float*)d_in[2];
  const float* cls   = (const float*)d_in[3];
  const float* pos   = (const float*)d_in[4];
  const float* ln1g  = (const float*)d_in[5];
  const float* ln1b  = (const float*)d_in[6];
  const float* qW    = (const float*)d_in[7];
  const float* qb    = (const float*)d_in[8];
  const float* kW    = (const float*)d_in[9];
  const float* kb    = (const float*)d_in[10];
  const float* vW    = (const float*)d_in[11];
  const float* vb    = (const float*)d_in[12];
  const float* oW    = (const float*)d_in[13];
  const float* ob    = (const float*)d_in[14];
  const float* proj  = (const float*)d_in[15];
  const float* ln2g  = (const float*)d_in[16];
  const float* ln2b  = (const float*)d_in[17];
  const float* fc1W  = (const float*)d_in[18];
  const float* fc1b  = (const float*)d_in[19];
  const float* fc2W  = (const float*)d_in[20];
  const float* fc2b  = (const float*)d_in[21];
  const float* lnfg  = (const float*)d_in[22];
  const float* lnfb  = (const float*)d_in[23];
  const float* headW = (const float*)d_in[24];
  const float* headb = (const float*)d_in[25];

  float* ws  = (float*)d_ws;
  u16*   wsu = (u16*)d_ws;
  float* X    = ws + F_X;
  float* KVP  = ws + F_KVP;
  float* KSP  = ws + F_KSP;
  float* KV   = ws + F_KV;
  float* KSUM = ws + F_KS;
  float* QKVB = ws + F_QKVB;
  u16* Ybf  = wsu + S_Y;
  u16* QKVb = wsu + S_QKV;
  u16* HB   = wsu + S_HB;
  u16* Wqkv = wsu + S_WQKV;
  u16* Wo   = wsu + S_WO;
  u16* Wf1  = wsu + S_WF1;
  u16* Wf2  = wsu + S_WF2;

  embed_k<<<BNT, 256, 0, stream>>>(ids, tok, cls, pos, X);
  for (int i = 0; i < L_; ++i) {
    const float* pj = proj + (size_t)i * H_ * HD_ * M_;
    wconv_k<<<3072, 256, 0, stream>>>(qW + (size_t)i * C_ * C_, kW + (size_t)i * C_ * C_,
        vW + (size_t)i * C_ * C_, oW + (size_t)i * C_ * C_,
        fc1W + (size_t)i * C_ * HID_, fc2W + (size_t)i * HID_ * C_,
        Wqkv, Wo, Wf1, Wf2);
    qkvb_k<<<6, 256, 0, stream>>>(qb + i * C_, kb + i * C_, vb + i * C_, QKVB);
    ln_bf_k<<<MPAD / 4, 256, 0, stream>>>(X, ln1g + i * C_, ln1b + i * C_, Ybf);
    gemm_bf_k<<<dim3(12, 129), 256, 0, stream>>>(Ybf, 512, Wqkv, QKVB,
        nullptr, QKVb, 1536, 512, MODE_QKV, attn);
    kvpart_k<<<dim3(8, 64), 256, 0, stream>>>(QKVb + 512, QKVb + 1024, pj, KVP, KSP);
    kvred_k<<<64, 256, 0, stream>>>(KVP, KSP, KV, KSUM);
    ctx_k<<<dim3(65, 64), 256, 0, stream>>>(QKVb, pj, KV, KSUM, Ybf);
    gemm_bf_k<<<dim3(4, 129), 256, 0, stream>>>(Ybf, 512, Wo, ob + i * C_,
        X, nullptr, 512, 512, MODE_RESID, attn);
    ln_bf_k<<<MPAD / 4, 256, 0, stream>>>(X, ln2g + i * C_, ln2b + i * C_, Ybf);
    for (int c2 = 0; c2 < 2; ++c2) {
      size_t rows0 = (size_t)c2 * 8320;
      int nb = c2 ? 64 : 65;
      gemm_bf_k<<<dim3(16, nb), 256, 0, stream>>>(Ybf + rows0 * 512, 512, Wf1,
          fc1b + i * HID_, nullptr, HB, 2048, 512, MODE_GELU, attn);
      gemm_bf_k<<<dim3(4, nb), 256, 0, stream>>>(HB, 2048, Wf2,
          fc2b + i * C_, X + rows0 * 512, nullptr, 512, 2048, MODE_RESID, attn);
    }
  }
  final_k<<<B_, 256, 0, stream>>>(X, lnfg, lnfb, headW, headb, (float*)d_out);
}

// Round 4
// 4621.409 us; speedup vs baseline: 5.0626x; 1.1765x over previous
//
#include <hip/hip_runtime.h>
#include <cmath>
#include <cstdint>
#include <cstddef>

#define B_ 8
#define N_ 2048
#define NT 2049
#define NP 2080                /* padded tokens per batch */
#define C_ 512
#define H_ 8
#define HD_ 64
#define L_ 8
#define M_ 128
#define HID_ 2048
#define NC_ 2
#define BNT (B_*NT)            /* 16392 valid rows */
#define RP (B_*NP)             /* 16640 padded rows = 130*128 */
#define SCALE_ 0.125f
#define LN_EPS_ 1e-5f
#define FEAT_EPS_ 1e-6f

#define MODE_QKV   1
#define MODE_GELU  2
#define MODE_RESID 3

typedef unsigned short u16;
typedef unsigned short u16x8 __attribute__((ext_vector_type(8)));
typedef short frag __attribute__((ext_vector_type(8)));
typedef float f32x4 __attribute__((ext_vector_type(4)));

// ---------------- workspace layout ----------------
// floats
constexpr size_t F_X    = 0;                         // RP*512 = 8,519,680
constexpr size_t F_KVP  = F_X   + (size_t)RP*512;    // 4*64*8192 = 2,097,152
constexpr size_t F_KSP  = F_KVP + (size_t)4*64*8192; // 32,768
constexpr size_t F_KV   = F_KSP + (size_t)4*64*128;  // 524,288
constexpr size_t F_KS   = F_KV  + (size_t)64*M_*HD_; // 8,192
constexpr size_t F_QKVB = F_KS  + (size_t)64*M_;     // 1,536
constexpr size_t F_END  = F_QKVB + 1536;             // 11,183,616 floats
// u16 region
constexpr size_t S_BASE  = 2 * F_END;
constexpr size_t S_YQF   = S_BASE;                        // RP*1024 (Y=first RP*512; QF full)
constexpr size_t S_QKV   = S_YQF  + (size_t)RP*1024;      // RP*1536 (HB 8320*2048 aliases)
constexpr size_t S_KFCTX = S_QKV  + (size_t)RP*1536;      // RP*1024 (KF full; CTX=first RP*512)
constexpr size_t S_WQKV  = S_KFCTX+ (size_t)RP*1024;      // 1536*512
constexpr size_t S_WO    = S_WQKV + (size_t)1536*512;     // 512*512
constexpr size_t S_WF1   = S_WO   + (size_t)512*512;      // 2048*512
constexpr size_t S_WF2   = S_WF1  + (size_t)2048*512;     // 512*2048
constexpr size_t S_PT    = S_WF2  + (size_t)512*2048;     // 8*128*64
constexpr size_t S_END   = S_PT   + (size_t)8*128*64;
constexpr size_t WS_BYTES = S_END * 2;                    // 170,432,512

// ---------------- helpers ----------------
__device__ __forceinline__ float wave_reduce(float v) {
#pragma unroll
  for (int off = 32; off > 0; off >>= 1) v += __shfl_down(v, off, 64);
  return v;
}
__device__ __forceinline__ float b2f(u16 u) {
  union { float f; uint32_t i; } v; v.i = ((uint32_t)u) << 16; return v.f;
}
__device__ __forceinline__ u16 f2b(float f) {
  union { float f; uint32_t i; } v; v.f = f;
  uint32_t r = v.i + 0x7FFF + ((v.i >> 16) & 1);
  return (u16)(r >> 16);
}
// global -> LDS direct staging: lds_base wave-uniform, lane writes base+lane*16B
__device__ __forceinline__ void gstage(const u16* g, u16* lds_base, int lane) {
#if __has_builtin(__builtin_amdgcn_global_load_lds)
  __builtin_amdgcn_global_load_lds((const __attribute__((address_space(1))) void*)g,
      (__attribute__((address_space(3))) void*)lds_base, 16, 0, 0);
#else
  *(u16x8*)(lds_base + lane * 8) = *(const u16x8*)g;
#endif
}

// ---------------- embedding ----------------
__global__ __launch_bounds__(256) void embed_k(const int* __restrict__ ids,
    const float* __restrict__ tok, const float* __restrict__ cls,
    const float* __restrict__ pos, float* __restrict__ X) {
  int row = blockIdx.x;
  int b = row / NT, n = row - b * NT;
  int t = threadIdx.x;
  const float* src = (n == 0) ? cls : tok + (size_t)ids[b * N_ + n - 1] * C_;
  size_t rp = (size_t)b * NP + n;
  X[rp * C_ + t]       = src[t]       + pos[(size_t)n * C_ + t];
  X[rp * C_ + t + 256] = src[t + 256] + pos[(size_t)n * C_ + t + 256];
}

// ---------------- weight transpose + convert + PT + qkv bias (per layer) ----------------
__global__ __launch_bounds__(256) void wconv_k(
    const float* __restrict__ qW, const float* __restrict__ kW,
    const float* __restrict__ vW, const float* __restrict__ oW,
    const float* __restrict__ f1W, const float* __restrict__ f2W,
    const float* __restrict__ projL,
    const float* __restrict__ qb, const float* __restrict__ kb,
    const float* __restrict__ vb,
    u16* __restrict__ Wqkv, u16* __restrict__ Wo,
    u16* __restrict__ Wf1, u16* __restrict__ Wf2,
    u16* __restrict__ PT, float* __restrict__ QKVB) {
  __shared__ float tile[32][33];
  int bid = blockIdx.x, t = threadIdx.x;
  if (bid >= 3104) {            // qkv bias concat
    int i = (bid - 3104) * 256 + t;
    QKVB[i] = (i < 512) ? qb[i] : (i < 1024) ? kb[i - 512] : vb[i - 1024];
    return;
  }
  if (bid >= 3072) {            // PT[h][m][d] = proj[h][d][m]
    int base = (bid - 3072) * 2048 + t * 8;
#pragma unroll
    for (int j = 0; j < 8; ++j) {
      int idx = base + j;
      int h = idx >> 13, rem = idx & 8191, m = rem >> 6, d = rem & 63;
      PT[idx] = f2b(projL[(size_t)h * 8192 + d * 128 + m]);
    }
    return;
  }
  int ti = t >> 5, tj = t & 31;
  const float* src; u16* dst; int k0, n0, ldn, ldk, scol;
  if (bid < 768) {
    int tk = bid & 15, tn = bid >> 4;
    k0 = tk * 32; n0 = tn * 32;
    int sel = n0 >> 9; scol = n0 & 511;
    src = (sel == 0) ? qW : (sel == 1) ? kW : vW;
    ldn = 512; dst = Wqkv; ldk = 512;
  } else if (bid < 1024) {
    int b2 = bid - 768;
    int tk = b2 & 15, tn = b2 >> 4;
    k0 = tk * 32; n0 = tn * 32; scol = n0;
    src = oW; ldn = 512; dst = Wo; ldk = 512;
  } else if (bid < 2048) {
    int b2 = bid - 1024;
    int tk = b2 & 15, tn = b2 >> 4;
    k0 = tk * 32; n0 = tn * 32; scol = n0;
    src = f1W; ldn = 2048; dst = Wf1; ldk = 512;
  } else {
    int b2 = bid - 2048;
    int tk = b2 & 63, tn = b2 >> 6;
    k0 = tk * 32; n0 = tn * 32; scol = n0;
    src = f2W; ldn = 512; dst = Wf2; ldk = 2048;
  }
  const float* sp = src + (size_t)k0 * ldn + scol;
  u16* dp = dst + (size_t)n0 * ldk + k0;
#pragma unroll
  for (int p = 0; p < 4; ++p)
    tile[ti + p * 8][tj] = sp[(size_t)(ti + p * 8) * ldn + tj];
  __syncthreads();
#pragma unroll
  for (int p = 0; p < 4; ++p)
    dp[(size_t)(ti + p * 8) * ldk + tj] = f2b(tile[tj][ti + p * 8]);
}

// ---------------- LayerNorm -> bf16 ----------------
__global__ __launch_bounds__(256) void ln_bf_k(const float* __restrict__ X,
    const float* __restrict__ g, const float* __restrict__ b,
    u16* __restrict__ Y) {
  int w = threadIdx.x >> 6, lane = threadIdx.x & 63;
  int row = blockIdx.x * 4 + w;
  const float* xr = X + (size_t)row * C_;
  float v[8];
  *(float4*)&v[0] = *(const float4*)(xr + lane * 8);
  *(float4*)&v[4] = *(const float4*)(xr + lane * 8 + 4);
  float s = 0.f;
#pragma unroll
  for (int j = 0; j < 8; ++j) s += v[j];
  s = wave_reduce(s);
  float mu = __shfl(s, 0, 64) * (1.0f / C_);
  float sq = 0.f;
#pragma unroll
  for (int j = 0; j < 8; ++j) { float d = v[j] - mu; sq = fmaf(d, d, sq); }
  sq = wave_reduce(sq);
  float rs = rsqrtf(__shfl(sq, 0, 64) * (1.0f / C_) + LN_EPS_);
  float gv[8], bv[8];
  *(float4*)&gv[0] = *(const float4*)(g + lane * 8);
  *(float4*)&gv[4] = *(const float4*)(g + lane * 8 + 4);
  *(float4*)&bv[0] = *(const float4*)(b + lane * 8);
  *(float4*)&bv[4] = *(const float4*)(b + lane * 8 + 4);
  u16x8 o;
#pragma unroll
  for (int j = 0; j < 8; ++j) o[j] = f2b((v[j] - mu) * rs * gv[j] + bv[j]);
  *(u16x8*)(Y + (size_t)row * C_ + lane * 8) = o;
}

// ---------------- bf16 MFMA GEMM, m97-style global_load_lds staging ----------------
// 128x128 tile, BK=32, 4 waves, each 64x64 via 4x4 mfma 16x16x32.
__global__ __launch_bounds__(256) void gemm_bf_k(
    const u16* __restrict__ A, int lda,
    const u16* __restrict__ Wt,          // [N][Kdim] bf16
    const float* __restrict__ bias,
    float* __restrict__ outF, u16* __restrict__ outB,
    int ldc, int Kdim, int mode, const int* __restrict__ attn) {
  __shared__ __align__(16) u16 As[128 * 32];
  __shared__ __align__(16) u16 Bs[128 * 32];
  const int t = threadIdx.x, w = t >> 6, l = t & 63;
  const int row0 = blockIdx.y * 128;
  const int col0 = blockIdx.x * 128;
  const int wm = w & 1, wn = w >> 1;
  const int lm = l & 15, lkb = l >> 4;
  const int srow = l >> 2, skof = (l & 3) * 8;
  const u16* Ag = A  + (size_t)row0 * lda  + (size_t)srow * lda  + skof;
  const u16* Bg = Wt + (size_t)col0 * Kdim + (size_t)srow * Kdim + skof;
  f32x4 acc[4][4] = {};
  for (int k0 = 0; k0 < Kdim; k0 += 32) {
    __syncthreads();
#pragma unroll
    for (int q = 0; q < 2; ++q) {
      int c = w * 2 + q;
      gstage(Ag + (size_t)c * 16 * lda  + k0, &As[c * 512], l);
      gstage(Bg + (size_t)c * 16 * Kdim + k0, &Bs[c * 512], l);
    }
    __syncthreads();
    frag af[4], bf4[4];
#pragma unroll
    for (int i = 0; i < 4; ++i)
      af[i] = *(const frag*)&As[(wm * 64 + i * 16 + lm) * 32 + lkb * 8];
#pragma unroll
    for (int j = 0; j < 4; ++j)
      bf4[j] = *(const frag*)&Bs[(wn * 64 + j * 16 + lm) * 32 + lkb * 8];
#pragma unroll
    for (int i = 0; i < 4; ++i)
#pragma unroll
      for (int j = 0; j < 4; ++j)
        acc[i][j] = __builtin_amdgcn_mfma_f32_16x16x32_bf16(af[i], bf4[j], acc[i][j], 0, 0, 0);
  }
#pragma unroll
  for (int i = 0; i < 4; ++i) {
#pragma unroll
    for (int j = 0; j < 4; ++j) {
      int gcol = col0 + wn * 64 + j * 16 + lm;
      float bia = bias[gcol];
#pragma unroll
      for (int r = 0; r < 4; ++r) {
        int grow = row0 + wm * 64 + i * 16 + lkb * 4 + r;
        float v = acc[i][j][r] + bia;
        if (mode == MODE_QKV) {
          if (gcol < 512) v *= SCALE_;
          else {
            int bb = grow / NP, nn = grow - bb * NP;
            if (nn != 0 && nn < NT) v *= (float)attn[bb * N_ + nn - 1];
          }
          outB[(size_t)grow * ldc + gcol] = f2b(v);
        } else if (mode == MODE_GELU) {
          v = 0.5f * v * (1.f + erff(v * 0.70710678118654752f));
          outB[(size_t)grow * ldc + gcol] = f2b(v);
        } else {
          outF[(size_t)grow * ldc + gcol] += v;
        }
      }
    }
  }
}

// ---------------- feature map via MFMA: OF = exp(x@P_h - 0.5|x|^2) + eps ----------------
// grid (130 row-blocks, 8 heads). A = QKVb slice (ld 1536), B = PT[h][128][64].
__global__ __launch_bounds__(256) void feat_k(const u16* __restrict__ Ain,
    const u16* __restrict__ PT, u16* __restrict__ OF) {
  __shared__ __align__(16) u16 As[128 * 64];
  __shared__ __align__(16) u16 Bs[128 * 64];
  __shared__ float sxe[128][2];
  const int t = threadIdx.x, w = t >> 6, l = t & 63;
  const int row0 = blockIdx.x * 128, h = blockIdx.y;
  const int wm = w & 1, wn = w >> 1;
  const int lm = l & 15, lkb = l >> 4;
  const u16* Ag = Ain + ((size_t)row0 + (l >> 3)) * 1536 + h * 64 + (l & 7) * 8;
  const u16* Bg = PT + (size_t)h * 8192 + (size_t)(l >> 3) * 64 + (l & 7) * 8;
#pragma unroll
  for (int q = 0; q < 4; ++q) {
    int c = w * 4 + q;
    gstage(Ag + (size_t)c * 8 * 1536, &As[c * 512], l);
    gstage(Bg + (size_t)c * 8 * 64,   &Bs[c * 512], l);
  }
  __syncthreads();
  {
    int r = t >> 1, hf = t & 1;
    const u16* ar = &As[r * 64 + hf * 32];
    float s = 0.f;
#pragma unroll
    for (int j2 = 0; j2 < 32; ++j2) { float a = b2f(ar[j2]); s = fmaf(a, a, s); }
    sxe[r][hf] = 0.5f * s;
  }
  f32x4 acc[4][4] = {};
#pragma unroll
  for (int ks = 0; ks < 2; ++ks) {
    frag af[4], bf4[4];
#pragma unroll
    for (int i = 0; i < 4; ++i)
      af[i] = *(const frag*)&As[(wm * 64 + i * 16 + lm) * 64 + ks * 32 + lkb * 8];
#pragma unroll
    for (int j = 0; j < 4; ++j)
      bf4[j] = *(const frag*)&Bs[(wn * 64 + j * 16 + lm) * 64 + ks * 32 + lkb * 8];
#pragma unroll
    for (int i = 0; i < 4; ++i)
#pragma unroll
      for (int j = 0; j < 4; ++j)
        acc[i][j] = __builtin_amdgcn_mfma_f32_16x16x32_bf16(af[i], bf4[j], acc[i][j], 0, 0, 0);
  }
  __syncthreads();
#pragma unroll
  for (int i = 0; i < 4; ++i) {
#pragma unroll
    for (int r = 0; r < 4; ++r) {
      int rl = wm * 64 + i * 16 + lkb * 4 + r;
      int grow = row0 + rl;
      int bb = grow / NP, nn = grow - bb * NP;
      bool valid = nn < NT;
      float xs = sxe[rl][0] + sxe[rl][1];
#pragma unroll
      for (int j = 0; j < 4; ++j) {
        int m = wn * 64 + j * 16 + lm;
        float v = valid ? (__expf(acc[i][j][r] - xs) + FEAT_EPS_) : 0.f;
        OF[(size_t)grow * 1024 + h * 128 + m] = f2b(v);
      }
    }
  }
}

// ---------------- kv partial (pure accumulation, fp32) ----------------
// grid (4 chunks of 520 tokens, 64 bh)
__global__ __launch_bounds__(256) void kvpart_k(const u16* __restrict__ KF,
    const u16* __restrict__ QKVb, float* __restrict__ KVP,
    float* __restrict__ KSP) {
  int ci = blockIdx.x, bh = blockIdx.y;
  int b = bh >> 3, h = bh & 7;
  size_t rb0 = (size_t)b * NP + ci * 520;
  __shared__ __align__(16) float kfs[8 * 132];
  __shared__ __align__(16) float vsm[8 * 68];
  int t = threadIdx.x;
  const int d0 = (t & 7) * 8, m0 = (t >> 3) * 4;
  float acc[4][8] = {};
  float ks[4] = {};
  for (int tile = 0; tile < 65; ++tile) {
    size_t rb = rb0 + tile * 8;
#pragma unroll
    for (int p = 0; p < 4; ++p) {
      int e = p * 256 + t; int m = e & 127; int tok = e >> 7;
      kfs[tok * 132 + m] = b2f(KF[(rb + tok) * 1024 + h * 128 + m]);
    }
#pragma unroll
    for (int p = 0; p < 2; ++p) {
      int e = p * 256 + t; int d = e & 63; int tok = e >> 6;
      vsm[tok * 68 + d] = b2f(QKVb[(rb + tok) * 1536 + 1024 + h * 64 + d]);
    }
    __syncthreads();
#pragma unroll
    for (int tok = 0; tok < 8; ++tok) {
      float kq[4], va[8];
      *(float4*)&kq[0] = *(const float4*)&kfs[tok * 132 + m0];
      *(float4*)&va[0] = *(const float4*)&vsm[tok * 68 + d0];
      *(float4*)&va[4] = *(const float4*)&vsm[tok * 68 + d0 + 4];
#pragma unroll
      for (int mi = 0; mi < 4; ++mi)
#pragma unroll
        for (int di = 0; di < 8; ++di)
          acc[mi][di] = fmaf(kq[mi], va[di], acc[mi][di]);
      if ((t & 7) == 0) { ks[0] += kq[0]; ks[1] += kq[1]; ks[2] += kq[2]; ks[3] += kq[3]; }
    }
    __syncthreads();
  }
  size_t base = ((size_t)ci * 64 + bh) * 8192;
#pragma unroll
  for (int mi = 0; mi < 4; ++mi)
#pragma unroll
    for (int di = 0; di < 8; ++di)
      KVP[base + (size_t)(m0 + mi) * 64 + d0 + di] = acc[mi][di];
  if ((t & 7) == 0) {
#pragma unroll
    for (int mi = 0; mi < 4; ++mi)
      KSP[((size_t)ci * 64 + bh) * 128 + m0 + mi] = ks[mi];
  }
}

__global__ __launch_bounds__(256) void kvred_k(const float* __restrict__ KVP,
    const float* __restrict__ KSP, float* __restrict__ KV,
    float* __restrict__ KSUM) {
  int bh = blockIdx.x, t = threadIdx.x;
#pragma unroll
  for (int p = 0; p < 32; ++p) {
    int e = p * 256 + t;
    float s = 0.f;
#pragma unroll
    for (int ci = 0; ci < 4; ++ci) s += KVP[((size_t)ci * 64 + bh) * 8192 + e];
    KV[(size_t)bh * 8192 + e] = s;
  }
  if (t < 128) {
    float s = 0.f;
#pragma unroll
    for (int ci = 0; ci < 4; ++ci) s += KSP[((size_t)ci * 64 + bh) * 128 + t];
    KSUM[(size_t)bh * 128 + t] = s;
  }
}

// ---------------- ctx: (qf @ kv) / max(qf . ksum, 1e-6), reads QF ----------------
__global__ __launch_bounds__(256) void ctx_k(const u16* __restrict__ QF,
    const float* __restrict__ KVg, const float* __restrict__ KSUM,
    u16* __restrict__ CTXo) {
  __shared__ float qfs[128 * 36];
  __shared__ float kvs[128 * 68];
  __shared__ float ksums[128];
  __shared__ float dls[32];
  __shared__ float dpart[8 * 32];
  int t = threadIdx.x;
  int bh = blockIdx.y; int b = bh >> 3, h = bh & 7;
  int n0 = blockIdx.x * 32;
  size_t rbase = (size_t)b * NP + n0;
#pragma unroll
  for (int p = 0; p < 16; ++p) {
    int e = p * 256 + t; int m = e & 127; int tok = e >> 7;
    qfs[m * 36 + tok] = b2f(QF[(rbase + tok) * 1024 + h * 128 + m]);
  }
#pragma unroll
  for (int p = 0; p < 32; ++p) {
    int e = p * 256 + t;
    kvs[(e >> 6) * 68 + (e & 63)] = KVg[(size_t)bh * 8192 + e];
  }
  if (t < 128) ksums[t] = KSUM[bh * 128 + t];
  __syncthreads();
  {
    int j = t & 31, pp = t >> 5;
    float s = 0.f;
#pragma unroll
    for (int mi = 0; mi < 16; ++mi) {
      int m = pp * 16 + mi;
      s = fmaf(qfs[m * 36 + j], ksums[m], s);
    }
    dpart[pp * 32 + j] = s;
  }
  __syncthreads();
  if (t < 32) {
    float den = 0.f;
#pragma unroll
    for (int pp = 0; pp < 8; ++pp) den += dpart[pp * 32 + t];
    dls[t] = 1.f / fmaxf(den, 1e-6f);
  }
  __syncthreads();
  {
    const int d0 = (t & 15) * 4, tok0 = (t >> 4) * 2;
    float acc[2][4] = {};
#pragma unroll 16
    for (int m = 0; m < 128; ++m) {
      float q0 = qfs[m * 36 + tok0];
      float q1 = qfs[m * 36 + tok0 + 1];
      float4 kv4 = *(const float4*)&kvs[m * 68 + d0];
      acc[0][0] = fmaf(q0, kv4.x, acc[0][0]); acc[0][1] = fmaf(q0, kv4.y, acc[0][1]);
      acc[0][2] = fmaf(q0, kv4.z, acc[0][2]); acc[0][3] = fmaf(q0, kv4.w, acc[0][3]);
      acc[1][0] = fmaf(q1, kv4.x, acc[1][0]); acc[1][1] = fmaf(q1, kv4.y, acc[1][1]);
      acc[1][2] = fmaf(q1, kv4.z, acc[1][2]); acc[1][3] = fmaf(q1, kv4.w, acc[1][3]);
    }
#pragma unroll
    for (int r = 0; r < 2; ++r) {
      int n = n0 + tok0 + r;
      if (n >= NT) continue;
      float rd = dls[tok0 + r];
      u16* o = CTXo + (rbase + tok0 + r) * C_ + h * HD_ + d0;
#pragma unroll
      for (int c = 0; c < 4; ++c) o[c] = f2b(acc[r][c] * rd);
    }
  }
}

// ---------------- final: LN(x[b,0]) @ headW + headb ----------------
__global__ __launch_bounds__(256) void final_k(const float* __restrict__ X,
    const float* __restrict__ g, const float* __restrict__ beta,
    const float* __restrict__ hW, const float* __restrict__ hb,
    float* __restrict__ out) {
  int b = blockIdx.x, t = threadIdx.x;
  const float* xr = X + (size_t)b * NP * C_;
  float v0 = xr[t], v1 = xr[t + 256];
  __shared__ float red[4][4];
  float s = wave_reduce(v0 + v1);
  if ((t & 63) == 0) red[0][t >> 6] = s;
  __syncthreads();
  float mu = (red[0][0] + red[0][1] + red[0][2] + red[0][3]) * (1.0f / C_);
  float d0 = v0 - mu, d1 = v1 - mu;
  float s2 = wave_reduce(d0 * d0 + d1 * d1);
  if ((t & 63) == 0) red[1][t >> 6] = s2;
  __syncthreads();
  float var = (red[1][0] + red[1][1] + red[1][2] + red[1][3]) * (1.0f / C_);
  float rs = rsqrtf(var + LN_EPS_);
  float n0 = d0 * rs * g[t] + beta[t];
  float n1 = d1 * rs * g[t + 256] + beta[t + 256];
  float p0 = n0 * hW[t * NC_]     + n1 * hW[(t + 256) * NC_];
  float p1 = n0 * hW[t * NC_ + 1] + n1 * hW[(t + 256) * NC_ + 1];
  float t0 = wave_reduce(p0);
  float t1 = wave_reduce(p1);
  if ((t & 63) == 0) { red[2][t >> 6] = t0; red[3][t >> 6] = t1; }
  __syncthreads();
  if (t == 0) {
    out[b * NC_]     = red[2][0] + red[2][1] + red[2][2] + red[2][3] + hb[0];
    out[b * NC_ + 1] = red[3][0] + red[3][1] + red[3][2] + red[3][3] + hb[1];
  }
}

// ---------------- launch ----------------
extern "C" void kernel_launch(void* const* d_in, const int* in_sizes, int n_in,
                              void* d_out, int out_size, void* d_ws, size_t ws_size,
                              hipStream_t stream) {
  if (ws_size < WS_BYTES) return;  // diagnostic guard
  const int*   ids   = (const int*)d_in[0];
  const int*   attn  = (const int*)d_in[1];
  const float* tok   = (const float*)d_in[2];
  const float* cls   = (const float*)d_in[3];
  const float* pos   = (const float*)d_in[4];
  const float* ln1g  = (const float*)d_in[5];
  const float* ln1b  = (const float*)d_in[6];
  const float* qW    = (const float*)d_in[7];
  const float* qb    = (const float*)d_in[8];
  const float* kW    = (const float*)d_in[9];
  const float* kb    = (const float*)d_in[10];
  const float* vW    = (const float*)d_in[11];
  const float* vb    = (const float*)d_in[12];
  const float* oW    = (const float*)d_in[13];
  const float* ob    = (const float*)d_in[14];
  const float* proj  = (const float*)d_in[15];
  const float* ln2g  = (const float*)d_in[16];
  const float* ln2b  = (const float*)d_in[17];
  const float* fc1W  = (const float*)d_in[18];
  const float* fc1b  = (const float*)d_in[19];
  const float* fc2W  = (const float*)d_in[20];
  const float* fc2b  = (const float*)d_in[21];
  const float* lnfg  = (const float*)d_in[22];
  const float* lnfb  = (const float*)d_in[23];
  const float* headW = (const float*)d_in[24];
  const float* headb = (const float*)d_in[25];

  float* ws  = (float*)d_ws;
  u16*   wsu = (u16*)d_ws;
  float* X    = ws + F_X;
  float* KVP  = ws + F_KVP;
  float* KSP  = ws + F_KSP;
  float* KV   = ws + F_KV;
  float* KSUM = ws + F_KS;
  float* QKVB = ws + F_QKVB;
  u16* Ybf  = wsu + S_YQF;    // [RP][512]
  u16* QFb  = wsu + S_YQF;    // [RP][1024] (aliases Y, temporally disjoint)
  u16* QKVb = wsu + S_QKV;    // [RP][1536]
  u16* HB   = wsu + S_QKV;    // [8320][2048] (aliases QKV, dead by FFN)
  u16* KFb  = wsu + S_KFCTX;  // [RP][1024]
  u16* CTXb = wsu + S_KFCTX;  // [RP][512] (aliases KF, dead by ctx)
  u16* Wqkv = wsu + S_WQKV;
  u16* Wo   = wsu + S_WO;
  u16* Wf1  = wsu + S_WF1;
  u16* Wf2  = wsu + S_WF2;
  u16* PT   = wsu + S_PT;

  embed_k<<<BNT, 256, 0, stream>>>(ids, tok, cls, pos, X);
  for (int i = 0; i < L_; ++i) {
    wconv_k<<<3110, 256, 0, stream>>>(qW + (size_t)i * C_ * C_, kW + (size_t)i * C_ * C_,
        vW + (size_t)i * C_ * C_, oW + (size_t)i * C_ * C_,
        fc1W + (size_t)i * C_ * HID_, fc2W + (size_t)i * HID_ * C_,
        proj + (size_t)i * H_ * HD_ * M_,
        qb + i * C_, kb + i * C_, vb + i * C_,
        Wqkv, Wo, Wf1, Wf2, PT, QKVB);
    ln_bf_k<<<RP / 4, 256, 0, stream>>>(X, ln1g + i * C_, ln1b + i * C_, Ybf);
    gemm_bf_k<<<dim3(12, 130), 256, 0, stream>>>(Ybf, 512, Wqkv, QKVB,
        nullptr, QKVb, 1536, 512, MODE_QKV, attn);
    feat_k<<<dim3(130, 8), 256, 0, stream>>>(QKVb, PT, QFb);
    feat_k<<<dim3(130, 8), 256, 0, stream>>>(QKVb + 512, PT, KFb);
    kvpart_k<<<dim3(4, 64), 256, 0, stream>>>(KFb, QKVb, KVP, KSP);
    kvred_k<<<64, 256, 0, stream>>>(KVP, KSP, KV, KSUM);
    ctx_k<<<dim3(65, 64), 256, 0, stream>>>(QFb, KV, KSUM, CTXb);
    gemm_bf_k<<<dim3(4, 130), 256, 0, stream>>>(CTXb, 512, Wo, ob + i * C_,
        X, nullptr, 512, 512, MODE_RESID, attn);
    ln_bf_k<<<RP / 4, 256, 0, stream>>>(X, ln2g + i * C_, ln2b + i * C_, Ybf);
    for (int c2 = 0; c2 < 2; ++c2) {
      size_t rows0 = (size_t)c2 * 8320;
      gemm_bf_k<<<dim3(16, 65), 256, 0, stream>>>(Ybf + rows0 * 512, 512, Wf1,
          fc1b + i * HID_, nullptr, HB, 2048, 512, MODE_GELU, attn);
      gemm_bf_k<<<dim3(4, 65), 256, 0, stream>>>(HB, 2048, Wf2,
          fc2b + i * C_, X + rows0 * 512, nullptr, 512, 2048, MODE_RESID, attn);
    }
  }
  final_k<<<B_, 256, 0, stream>>>(X, lnfg, lnfb, headW, headb, (float*)d_out);
}

// Round 5
// 3742.502 us; speedup vs baseline: 6.2516x; 1.2348x over previous
//
#include <hip/hip_runtime.h>
#include <cmath>
#include <cstdint>
#include <cstddef>

#define B_ 8
#define N_ 2048
#define NT 2049
#define NP 2080                /* padded tokens per batch */
#define C_ 512
#define H_ 8
#define HD_ 64
#define L_ 8
#define M_ 128
#define HID_ 2048
#define NC_ 2
#define BNT (B_*NT)            /* 16392 valid rows */
#define RP (B_*NP)             /* 16640 padded rows = 130*128 */
#define SCALE_ 0.125f
#define LN_EPS_ 1e-5f
#define FEAT_EPS_ 1e-6f

#define MODE_QKV   1
#define MODE_GELU  2
#define MODE_RESID 3

typedef unsigned short u16;
typedef unsigned short u16x8 __attribute__((ext_vector_type(8)));
typedef short frag __attribute__((ext_vector_type(8)));
typedef float f32x4 __attribute__((ext_vector_type(4)));

// ---------------- workspace layout ----------------
// floats
constexpr size_t F_X    = 0;                         // RP*512 = 8,519,680
constexpr size_t F_KVP  = F_X   + (size_t)RP*512;    // 4*64*8192 = 2,097,152
constexpr size_t F_KSP  = F_KVP + (size_t)4*64*8192; // 32,768
constexpr size_t F_KV   = F_KSP + (size_t)4*64*128;  // 524,288
constexpr size_t F_KS   = F_KV  + (size_t)64*M_*HD_; // 8,192
constexpr size_t F_QKVB = F_KS  + (size_t)64*M_;     // 1,536
constexpr size_t F_END  = F_QKVB + 1536;
// u16 region
constexpr size_t S_BASE  = 2 * F_END;
constexpr size_t S_YQF   = S_BASE;                        // RP*1024 (Y=first RP*512; QF full)
constexpr size_t S_QKV   = S_YQF  + (size_t)RP*1024;      // RP*1536
constexpr size_t S_KFCTX = S_QKV  + (size_t)RP*1536;      // RP*1024 (KF full; CTX=first RP*512)
constexpr size_t S_WQKV  = S_KFCTX+ (size_t)RP*1024;      // 1536*512
constexpr size_t S_WO    = S_WQKV + (size_t)1536*512;     // 512*512
constexpr size_t S_WF1   = S_WO   + (size_t)512*512;      // 2048*512
constexpr size_t S_WF2   = S_WF1  + (size_t)2048*512;     // 512*2048
constexpr size_t S_PT    = S_WF2  + (size_t)512*2048;     // 8*128*64
constexpr size_t S_END   = S_PT   + (size_t)8*128*64;
constexpr size_t WS_BYTES = S_END * 2;                    // 170,432,512
// HB[RP][2048] aliases the freed QF-upper + QKV + KF span (starts right after Y)

// ---------------- helpers ----------------
__device__ __forceinline__ float wave_reduce(float v) {
#pragma unroll
  for (int off = 32; off > 0; off >>= 1) v += __shfl_down(v, off, 64);
  return v;
}
__device__ __forceinline__ float b2f(u16 u) {
  union { float f; uint32_t i; } v; v.i = ((uint32_t)u) << 16; return v.f;
}
__device__ __forceinline__ u16 f2b(float f) {
  union { float f; uint32_t i; } v; v.f = f;
  uint32_t r = v.i + 0x7FFF + ((v.i >> 16) & 1);
  return (u16)(r >> 16);
}
// global -> LDS direct staging: lds_base wave-uniform, lane writes base+lane*16B
__device__ __forceinline__ void gstage(const u16* g, u16* lds_base, int lane) {
#if __has_builtin(__builtin_amdgcn_global_load_lds)
  __builtin_amdgcn_global_load_lds((const __attribute__((address_space(1))) void*)g,
      (__attribute__((address_space(3))) void*)lds_base, 16, 0, 0);
#else
  *(u16x8*)(lds_base + lane * 8) = *(const u16x8*)g;
#endif
}

// ---------------- embedding ----------------
__global__ __launch_bounds__(256) void embed_k(const int* __restrict__ ids,
    const float* __restrict__ tok, const float* __restrict__ cls,
    const float* __restrict__ pos, float* __restrict__ X) {
  int row = blockIdx.x;
  int b = row / NT, n = row - b * NT;
  int t = threadIdx.x;
  const float* src = (n == 0) ? cls : tok + (size_t)ids[b * N_ + n - 1] * C_;
  size_t rp = (size_t)b * NP + n;
  X[rp * C_ + t]       = src[t]       + pos[(size_t)n * C_ + t];
  X[rp * C_ + t + 256] = src[t + 256] + pos[(size_t)n * C_ + t + 256];
}

// ---------------- weight transpose + convert + PT + qkv bias (per layer) ----------------
__global__ __launch_bounds__(256) void wconv_k(
    const float* __restrict__ qW, const float* __restrict__ kW,
    const float* __restrict__ vW, const float* __restrict__ oW,
    const float* __restrict__ f1W, const float* __restrict__ f2W,
    const float* __restrict__ projL,
    const float* __restrict__ qb, const float* __restrict__ kb,
    const float* __restrict__ vb,
    u16* __restrict__ Wqkv, u16* __restrict__ Wo,
    u16* __restrict__ Wf1, u16* __restrict__ Wf2,
    u16* __restrict__ PT, float* __restrict__ QKVB) {
  __shared__ float tile[32][33];
  int bid = blockIdx.x, t = threadIdx.x;
  if (bid >= 3104) {            // qkv bias concat
    int i = (bid - 3104) * 256 + t;
    QKVB[i] = (i < 512) ? qb[i] : (i < 1024) ? kb[i - 512] : vb[i - 1024];
    return;
  }
  if (bid >= 3072) {            // PT[h][m][d] = proj[h][d][m]
    int base = (bid - 3072) * 2048 + t * 8;
#pragma unroll
    for (int j = 0; j < 8; ++j) {
      int idx = base + j;
      int h = idx >> 13, rem = idx & 8191, m = rem >> 6, d = rem & 63;
      PT[idx] = f2b(projL[(size_t)h * 8192 + d * 128 + m]);
    }
    return;
  }
  int ti = t >> 5, tj = t & 31;
  const float* src; u16* dst; int k0, n0, ldn, ldk, scol;
  if (bid < 768) {
    int tk = bid & 15, tn = bid >> 4;
    k0 = tk * 32; n0 = tn * 32;
    int sel = n0 >> 9; scol = n0 & 511;
    src = (sel == 0) ? qW : (sel == 1) ? kW : vW;
    ldn = 512; dst = Wqkv; ldk = 512;
  } else if (bid < 1024) {
    int b2 = bid - 768;
    int tk = b2 & 15, tn = b2 >> 4;
    k0 = tk * 32; n0 = tn * 32; scol = n0;
    src = oW; ldn = 512; dst = Wo; ldk = 512;
  } else if (bid < 2048) {
    int b2 = bid - 1024;
    int tk = b2 & 15, tn = b2 >> 4;
    k0 = tk * 32; n0 = tn * 32; scol = n0;
    src = f1W; ldn = 2048; dst = Wf1; ldk = 512;
  } else {
    int b2 = bid - 2048;
    int tk = b2 & 63, tn = b2 >> 6;
    k0 = tk * 32; n0 = tn * 32; scol = n0;
    src = f2W; ldn = 512; dst = Wf2; ldk = 2048;
  }
  const float* sp = src + (size_t)k0 * ldn + scol;
  u16* dp = dst + (size_t)n0 * ldk + k0;
#pragma unroll
  for (int p = 0; p < 4; ++p)
    tile[ti + p * 8][tj] = sp[(size_t)(ti + p * 8) * ldn + tj];
  __syncthreads();
#pragma unroll
  for (int p = 0; p < 4; ++p)
    dp[(size_t)(ti + p * 8) * ldk + tj] = f2b(tile[tj][ti + p * 8]);
}

// ---------------- LayerNorm -> bf16 ----------------
__global__ __launch_bounds__(256) void ln_bf_k(const float* __restrict__ X,
    const float* __restrict__ g, const float* __restrict__ b,
    u16* __restrict__ Y) {
  int w = threadIdx.x >> 6, lane = threadIdx.x & 63;
  int row = blockIdx.x * 4 + w;
  const float* xr = X + (size_t)row * C_;
  float v[8];
  *(float4*)&v[0] = *(const float4*)(xr + lane * 8);
  *(float4*)&v[4] = *(const float4*)(xr + lane * 8 + 4);
  float s = 0.f;
#pragma unroll
  for (int j = 0; j < 8; ++j) s += v[j];
  s = wave_reduce(s);
  float mu = __shfl(s, 0, 64) * (1.0f / C_);
  float sq = 0.f;
#pragma unroll
  for (int j = 0; j < 8; ++j) { float d = v[j] - mu; sq = fmaf(d, d, sq); }
  sq = wave_reduce(sq);
  float rs = rsqrtf(__shfl(sq, 0, 64) * (1.0f / C_) + LN_EPS_);
  float gv[8], bv[8];
  *(float4*)&gv[0] = *(const float4*)(g + lane * 8);
  *(float4*)&gv[4] = *(const float4*)(g + lane * 8 + 4);
  *(float4*)&bv[0] = *(const float4*)(b + lane * 8);
  *(float4*)&bv[4] = *(const float4*)(b + lane * 8 + 4);
  u16x8 o;
#pragma unroll
  for (int j = 0; j < 8; ++j) o[j] = f2b((v[j] - mu) * rs * gv[j] + bv[j]);
  *(u16x8*)(Y + (size_t)row * C_ + lane * 8) = o;
}

// ---------------- bf16 MFMA GEMM: BK=64, XOR-swizzled LDS (conflict-free) ------
// 128x128 tile, 4 waves each 64x64 via 4x4 mfma 16x16x32; global_load_lds 16B.
// LDS layout: row r (64 shorts), 16B-chunk c stored at chunk slot (c ^ (r&7)).
// The swizzle is applied on the per-lane GLOBAL gather address, since the LDS
// destination of global_load_lds is fixed linear (base + lane*16B).
__global__ __launch_bounds__(256) void gemm_bf_k(
    const u16* __restrict__ A, int lda,
    const u16* __restrict__ Wt,          // [N][Kdim] bf16
    const float* __restrict__ bias,
    float* __restrict__ outF, u16* __restrict__ outB,
    int ldc, int Kdim, int mode, const int* __restrict__ attn) {
  __shared__ __align__(16) u16 As[128 * 64];
  __shared__ __align__(16) u16 Bs[128 * 64];
  const int t = threadIdx.x, w = t >> 6, l = t & 63;
  const int row0 = blockIdx.y * 128, col0 = blockIdx.x * 128;
  const int wm = w & 1, wn = w >> 1;
  const int lm = l & 15, lkb = l >> 4;
  const int lr = l >> 3, lc = l & 7;          // staging: row-in-8-group, chunk slot
  const int kch = (lc ^ lr) * 8;              // swizzled source k-chunk (shorts)
  const u16* Ag = A  + (size_t)(row0 + lr) * lda  + kch;
  const u16* Bg = Wt + (size_t)(col0 + lr) * Kdim + kch;
  const int sx = lm & 7;                      // read-side swizzle key
  f32x4 acc[4][4] = {};
  for (int k0 = 0; k0 < Kdim; k0 += 64) {
    __syncthreads();
#pragma unroll
    for (int j = 0; j < 4; ++j) {
      int c8 = w * 4 + j;                     // 8-row group 0..15
      gstage(Ag + (size_t)c8 * 8 * lda  + k0, &As[c8 * 512], l);
      gstage(Bg + (size_t)c8 * 8 * Kdim + k0, &Bs[c8 * 512], l);
    }
    __syncthreads();
#pragma unroll
    for (int ks = 0; ks < 2; ++ks) {
      frag af[4], bf4[4];
#pragma unroll
      for (int i = 0; i < 4; ++i)
        af[i] = *(const frag*)&As[(wm * 64 + i * 16 + lm) * 64 + (((ks * 4 + lkb) ^ sx) * 8)];
#pragma unroll
      for (int j = 0; j < 4; ++j)
        bf4[j] = *(const frag*)&Bs[(wn * 64 + j * 16 + lm) * 64 + (((ks * 4 + lkb) ^ sx) * 8)];
#pragma unroll
      for (int i = 0; i < 4; ++i)
#pragma unroll
        for (int j = 0; j < 4; ++j)
          acc[i][j] = __builtin_amdgcn_mfma_f32_16x16x32_bf16(af[i], bf4[j], acc[i][j], 0, 0, 0);
    }
  }
#pragma unroll
  for (int i = 0; i < 4; ++i) {
#pragma unroll
    for (int r = 0; r < 4; ++r) {
      int grow = row0 + wm * 64 + i * 16 + lkb * 4 + r;
      if (mode == MODE_RESID) {
        float* orow = outF + (size_t)grow * ldc + col0;
#pragma unroll
        for (int j = 0; j < 4; ++j) {
          int gc = wn * 64 + j * 16 + lm;
          orow[gc] += acc[i][j][r] + bias[col0 + gc];
        }
      } else if (mode == MODE_QKV) {
        int bb = grow / NP, nn = grow - bb * NP;
        float mrow = (nn == 0) ? 1.f : (nn < NT ? (float)attn[bb * N_ + nn - 1] : 0.f);
        u16* orow = outB + (size_t)grow * ldc + col0;
#pragma unroll
        for (int j = 0; j < 4; ++j) {
          int gc = wn * 64 + j * 16 + lm;
          float v = acc[i][j][r] + bias[col0 + gc];
          v *= ((col0 + gc) < 512) ? SCALE_ : mrow;
          orow[gc] = f2b(v);
        }
      } else { // MODE_GELU
        u16* orow = outB + (size_t)grow * ldc + col0;
#pragma unroll
        for (int j = 0; j < 4; ++j) {
          int gc = wn * 64 + j * 16 + lm;
          float v = acc[i][j][r] + bias[col0 + gc];
          v = 0.5f * v * (1.f + erff(v * 0.70710678118654752f));
          orow[gc] = f2b(v);
        }
      }
    }
  }
}

// ---------------- feature map via MFMA: OF = exp(x@P_h - 0.5|x|^2) + eps ------
// grid (130 row-blocks, 8 heads). A = QKVb slice (ld 1536), B = PT[h][128][64].
// Same XOR-swizzled LDS layout as gemm_bf_k.
__global__ __launch_bounds__(256) void feat_k(const u16* __restrict__ Ain,
    const u16* __restrict__ PT, u16* __restrict__ OF) {
  __shared__ __align__(16) u16 As[128 * 64];
  __shared__ __align__(16) u16 Bs[128 * 64];
  __shared__ float sxe[128][2];
  const int t = threadIdx.x, w = t >> 6, l = t & 63;
  const int row0 = blockIdx.x * 128, h = blockIdx.y;
  const int wm = w & 1, wn = w >> 1;
  const int lm = l & 15, lkb = l >> 4;
  const int lr = l >> 3, lc = l & 7;
  const int kch = (lc ^ lr) * 8;
  const u16* Ag = Ain + ((size_t)row0 + lr) * 1536 + h * 64 + kch;
  const u16* Bg = PT + (size_t)h * 8192 + (size_t)lr * 64 + kch;
#pragma unroll
  for (int q = 0; q < 4; ++q) {
    int c8 = w * 4 + q;
    gstage(Ag + (size_t)c8 * 8 * 1536, &As[c8 * 512], l);
    gstage(Bg + (size_t)c8 * 8 * 64,   &Bs[c8 * 512], l);
  }
  __syncthreads();
  {
    int r = t >> 1, hf = t & 1;
    float s = 0.f;
#pragma unroll
    for (int cc = 0; cc < 4; ++cc) {
      const u16* ar = &As[r * 64 + (((hf * 4 + cc) ^ (r & 7)) * 8)];
#pragma unroll
      for (int j2 = 0; j2 < 8; ++j2) { float a = b2f(ar[j2]); s = fmaf(a, a, s); }
    }
    sxe[r][hf] = 0.5f * s;
  }
  const int sx = lm & 7;
  f32x4 acc[4][4] = {};
#pragma unroll
  for (int ks = 0; ks < 2; ++ks) {
    frag af[4], bf4[4];
#pragma unroll
    for (int i = 0; i < 4; ++i)
      af[i] = *(const frag*)&As[(wm * 64 + i * 16 + lm) * 64 + (((ks * 4 + lkb) ^ sx) * 8)];
#pragma unroll
    for (int j = 0; j < 4; ++j)
      bf4[j] = *(const frag*)&Bs[(wn * 64 + j * 16 + lm) * 64 + (((ks * 4 + lkb) ^ sx) * 8)];
#pragma unroll
    for (int i = 0; i < 4; ++i)
#pragma unroll
      for (int j = 0; j < 4; ++j)
        acc[i][j] = __builtin_amdgcn_mfma_f32_16x16x32_bf16(af[i], bf4[j], acc[i][j], 0, 0, 0);
  }
  __syncthreads();
#pragma unroll
  for (int i = 0; i < 4; ++i) {
#pragma unroll
    for (int r = 0; r < 4; ++r) {
      int rl = wm * 64 + i * 16 + lkb * 4 + r;
      int grow = row0 + rl;
      int bb = grow / NP, nn = grow - bb * NP;
      bool valid = nn < NT;
      float xs = sxe[rl][0] + sxe[rl][1];
#pragma unroll
      for (int j = 0; j < 4; ++j) {
        int m = wn * 64 + j * 16 + lm;
        float v = valid ? (__expf(acc[i][j][r] - xs) + FEAT_EPS_) : 0.f;
        OF[(size_t)grow * 1024 + h * 128 + m] = f2b(v);
      }
    }
  }
}

// ---------------- kv partial (pure accumulation, fp32) ----------------
__global__ __launch_bounds__(256) void kvpart_k(const u16* __restrict__ KF,
    const u16* __restrict__ QKVb, float* __restrict__ KVP,
    float* __restrict__ KSP) {
  int ci = blockIdx.x, bh = blockIdx.y;
  int b = bh >> 3, h = bh & 7;
  size_t rb0 = (size_t)b * NP + ci * 520;
  __shared__ __align__(16) float kfs[8 * 132];
  __shared__ __align__(16) float vsm[8 * 68];
  int t = threadIdx.x;
  const int d0 = (t & 7) * 8, m0 = (t >> 3) * 4;
  float acc[4][8] = {};
  float ks[4] = {};
  for (int tile = 0; tile < 65; ++tile) {
    size_t rb = rb0 + tile * 8;
#pragma unroll
    for (int p = 0; p < 4; ++p) {
      int e = p * 256 + t; int m = e & 127; int tok = e >> 7;
      kfs[tok * 132 + m] = b2f(KF[(rb + tok) * 1024 + h * 128 + m]);
    }
#pragma unroll
    for (int p = 0; p < 2; ++p) {
      int e = p * 256 + t; int d = e & 63; int tok = e >> 6;
      vsm[tok * 68 + d] = b2f(QKVb[(rb + tok) * 1536 + 1024 + h * 64 + d]);
    }
    __syncthreads();
#pragma unroll
    for (int tok = 0; tok < 8; ++tok) {
      float kq[4], va[8];
      *(float4*)&kq[0] = *(const float4*)&kfs[tok * 132 + m0];
      *(float4*)&va[0] = *(const float4*)&vsm[tok * 68 + d0];
      *(float4*)&va[4] = *(const float4*)&vsm[tok * 68 + d0 + 4];
#pragma unroll
      for (int mi = 0; mi < 4; ++mi)
#pragma unroll
        for (int di = 0; di < 8; ++di)
          acc[mi][di] = fmaf(kq[mi], va[di], acc[mi][di]);
      if ((t & 7) == 0) { ks[0] += kq[0]; ks[1] += kq[1]; ks[2] += kq[2]; ks[3] += kq[3]; }
    }
    __syncthreads();
  }
  size_t base = ((size_t)ci * 64 + bh) * 8192;
#pragma unroll
  for (int mi = 0; mi < 4; ++mi)
#pragma unroll
    for (int di = 0; di < 8; ++di)
      KVP[base + (size_t)(m0 + mi) * 64 + d0 + di] = acc[mi][di];
  if ((t & 7) == 0) {
#pragma unroll
    for (int mi = 0; mi < 4; ++mi)
      KSP[((size_t)ci * 64 + bh) * 128 + m0 + mi] = ks[mi];
  }
}

__global__ __launch_bounds__(256) void kvred_k(const float* __restrict__ KVP,
    const float* __restrict__ KSP, float* __restrict__ KV,
    float* __restrict__ KSUM) {
  int bh = blockIdx.x, t = threadIdx.x;
#pragma unroll
  for (int p = 0; p < 32; ++p) {
    int e = p * 256 + t;
    float s = 0.f;
#pragma unroll
    for (int ci = 0; ci < 4; ++ci) s += KVP[((size_t)ci * 64 + bh) * 8192 + e];
    KV[(size_t)bh * 8192 + e] = s;
  }
  if (t < 128) {
    float s = 0.f;
#pragma unroll
    for (int ci = 0; ci < 4; ++ci) s += KSP[((size_t)ci * 64 + bh) * 128 + t];
    KSUM[(size_t)bh * 128 + t] = s;
  }
}

// ---------------- ctx: (qf @ kv) / max(qf . ksum, 1e-6) ----------------
__global__ __launch_bounds__(256) void ctx_k(const u16* __restrict__ QF,
    const float* __restrict__ KVg, const float* __restrict__ KSUM,
    u16* __restrict__ CTXo) {
  __shared__ float qfs[128 * 36];
  __shared__ float kvs[128 * 68];
  __shared__ float ksums[128];
  __shared__ float dls[32];
  __shared__ float dpart[8 * 32];
  int t = threadIdx.x;
  int bh = blockIdx.y; int b = bh >> 3, h = bh & 7;
  int n0 = blockIdx.x * 32;
  size_t rbase = (size_t)b * NP + n0;
#pragma unroll
  for (int p = 0; p < 16; ++p) {
    int e = p * 256 + t; int m = e & 127; int tok = e >> 7;
    qfs[m * 36 + tok] = b2f(QF[(rbase + tok) * 1024 + h * 128 + m]);
  }
#pragma unroll
  for (int p = 0; p < 32; ++p) {
    int e = p * 256 + t;
    kvs[(e >> 6) * 68 + (e & 63)] = KVg[(size_t)bh * 8192 + e];
  }
  if (t < 128) ksums[t] = KSUM[bh * 128 + t];
  __syncthreads();
  {
    int j = t & 31, pp = t >> 5;
    float s = 0.f;
#pragma unroll
    for (int mi = 0; mi < 16; ++mi) {
      int m = pp * 16 + mi;
      s = fmaf(qfs[m * 36 + j], ksums[m], s);
    }
    dpart[pp * 32 + j] = s;
  }
  __syncthreads();
  if (t < 32) {
    float den = 0.f;
#pragma unroll
    for (int pp = 0; pp < 8; ++pp) den += dpart[pp * 32 + t];
    dls[t] = 1.f / fmaxf(den, 1e-6f);
  }
  __syncthreads();
  {
    const int d0 = (t & 15) * 4, tok0 = (t >> 4) * 2;
    float acc[2][4] = {};
#pragma unroll 16
    for (int m = 0; m < 128; ++m) {
      float q0 = qfs[m * 36 + tok0];
      float q1 = qfs[m * 36 + tok0 + 1];
      float4 kv4 = *(const float4*)&kvs[m * 68 + d0];
      acc[0][0] = fmaf(q0, kv4.x, acc[0][0]); acc[0][1] = fmaf(q0, kv4.y, acc[0][1]);
      acc[0][2] = fmaf(q0, kv4.z, acc[0][2]); acc[0][3] = fmaf(q0, kv4.w, acc[0][3]);
      acc[1][0] = fmaf(q1, kv4.x, acc[1][0]); acc[1][1] = fmaf(q1, kv4.y, acc[1][1]);
      acc[1][2] = fmaf(q1, kv4.z, acc[1][2]); acc[1][3] = fmaf(q1, kv4.w, acc[1][3]);
    }
#pragma unroll
    for (int r = 0; r < 2; ++r) {
      int n = n0 + tok0 + r;
      if (n >= NT) continue;
      float rd = dls[tok0 + r];
      u16* o = CTXo + (rbase + tok0 + r) * C_ + h * HD_ + d0;
#pragma unroll
      for (int c = 0; c < 4; ++c) o[c] = f2b(acc[r][c] * rd);
    }
  }
}

// ---------------- final: LN(x[b,0]) @ headW + headb ----------------
__global__ __launch_bounds__(256) void final_k(const float* __restrict__ X,
    const float* __restrict__ g, const float* __restrict__ beta,
    const float* __restrict__ hW, const float* __restrict__ hb,
    float* __restrict__ out) {
  int b = blockIdx.x, t = threadIdx.x;
  const float* xr = X + (size_t)b * NP * C_;
  float v0 = xr[t], v1 = xr[t + 256];
  __shared__ float red[4][4];
  float s = wave_reduce(v0 + v1);
  if ((t & 63) == 0) red[0][t >> 6] = s;
  __syncthreads();
  float mu = (red[0][0] + red[0][1] + red[0][2] + red[0][3]) * (1.0f / C_);
  float d0 = v0 - mu, d1 = v1 - mu;
  float s2 = wave_reduce(d0 * d0 + d1 * d1);
  if ((t & 63) == 0) red[1][t >> 6] = s2;
  __syncthreads();
  float var = (red[1][0] + red[1][1] + red[1][2] + red[1][3]) * (1.0f / C_);
  float rs = rsqrtf(var + LN_EPS_);
  float n0 = d0 * rs * g[t] + beta[t];
  float n1 = d1 * rs * g[t + 256] + beta[t + 256];
  float p0 = n0 * hW[t * NC_]     + n1 * hW[(t + 256) * NC_];
  float p1 = n0 * hW[t * NC_ + 1] + n1 * hW[(t + 256) * NC_ + 1];
  float t0 = wave_reduce(p0);
  float t1 = wave_reduce(p1);
  if ((t & 63) == 0) { red[2][t >> 6] = t0; red[3][t >> 6] = t1; }
  __syncthreads();
  if (t == 0) {
    out[b * NC_]     = red[2][0] + red[2][1] + red[2][2] + red[2][3] + hb[0];
    out[b * NC_ + 1] = red[3][0] + red[3][1] + red[3][2] + red[3][3] + hb[1];
  }
}

// ---------------- launch ----------------
extern "C" void kernel_launch(void* const* d_in, const int* in_sizes, int n_in,
                              void* d_out, int out_size, void* d_ws, size_t ws_size,
                              hipStream_t stream) {
  if (ws_size < WS_BYTES) return;  // diagnostic guard
  const int*   ids   = (const int*)d_in[0];
  const int*   attn  = (const int*)d_in[1];
  const float* tok   = (const float*)d_in[2];
  const float* cls   = (const float*)d_in[3];
  const float* pos   = (const float*)d_in[4];
  const float* ln1g  = (const float*)d_in[5];
  const float* ln1b  = (const float*)d_in[6];
  const float* qW    = (const float*)d_in[7];
  const float* qb    = (const float*)d_in[8];
  const float* kW    = (const float*)d_in[9];
  const float* kb    = (const float*)d_in[10];
  const float* vW    = (const float*)d_in[11];
  const float* vb    = (const float*)d_in[12];
  const float* oW    = (const float*)d_in[13];
  const float* ob    = (const float*)d_in[14];
  const float* proj  = (const float*)d_in[15];
  const float* ln2g  = (const float*)d_in[16];
  const float* ln2b  = (const float*)d_in[17];
  const float* fc1W  = (const float*)d_in[18];
  const float* fc1b  = (const float*)d_in[19];
  const float* fc2W  = (const float*)d_in[20];
  const float* fc2b  = (const float*)d_in[21];
  const float* lnfg  = (const float*)d_in[22];
  const float* lnfb  = (const float*)d_in[23];
  const float* headW = (const float*)d_in[24];
  const float* headb = (const float*)d_in[25];

  float* ws  = (float*)d_ws;
  u16*   wsu = (u16*)d_ws;
  float* X    = ws + F_X;
  float* KVP  = ws + F_KVP;
  float* KSP  = ws + F_KSP;
  float* KV   = ws + F_KV;
  float* KSUM = ws + F_KS;
  float* QKVB = ws + F_QKVB;
  u16* Ybf  = wsu + S_YQF;                      // [RP][512]
  u16* QFb  = wsu + S_YQF;                      // [RP][1024] (aliases Y)
  u16* QKVb = wsu + S_QKV;                      // [RP][1536]
  u16* HB   = wsu + S_YQF + (size_t)RP * 512;   // [RP][2048] (aliases QF-hi+QKV+KF-part, dead regions by FFN)
  u16* KFb  = wsu + S_KFCTX;                    // [RP][1024]
  u16* CTXb = wsu + S_KFCTX;                    // [RP][512] (aliases KF)
  u16* Wqkv = wsu + S_WQKV;
  u16* Wo   = wsu + S_WO;
  u16* Wf1  = wsu + S_WF1;
  u16* Wf2  = wsu + S_WF2;
  u16* PT   = wsu + S_PT;

  embed_k<<<BNT, 256, 0, stream>>>(ids, tok, cls, pos, X);
  for (int i = 0; i < L_; ++i) {
    wconv_k<<<3110, 256, 0, stream>>>(qW + (size_t)i * C_ * C_, kW + (size_t)i * C_ * C_,
        vW + (size_t)i * C_ * C_, oW + (size_t)i * C_ * C_,
        fc1W + (size_t)i * C_ * HID_, fc2W + (size_t)i * HID_ * C_,
        proj + (size_t)i * H_ * HD_ * M_,
        qb + i * C_, kb + i * C_, vb + i * C_,
        Wqkv, Wo, Wf1, Wf2, PT, QKVB);
    ln_bf_k<<<RP / 4, 256, 0, stream>>>(X, ln1g + i * C_, ln1b + i * C_, Ybf);
    gemm_bf_k<<<dim3(12, 130), 256, 0, stream>>>(Ybf, 512, Wqkv, QKVB,
        nullptr, QKVb, 1536, 512, MODE_QKV, attn);
    feat_k<<<dim3(130, 8), 256, 0, stream>>>(QKVb, PT, QFb);
    feat_k<<<dim3(130, 8), 256, 0, stream>>>(QKVb + 512, PT, KFb);
    kvpart_k<<<dim3(4, 64), 256, 0, stream>>>(KFb, QKVb, KVP, KSP);
    kvred_k<<<64, 256, 0, stream>>>(KVP, KSP, KV, KSUM);
    ctx_k<<<dim3(65, 64), 256, 0, stream>>>(QFb, KV, KSUM, CTXb);
    gemm_bf_k<<<dim3(4, 130), 256, 0, stream>>>(CTXb, 512, Wo, ob + i * C_,
        X, nullptr, 512, 512, MODE_RESID, attn);
    ln_bf_k<<<RP / 4, 256, 0, stream>>>(X, ln2g + i * C_, ln2b + i * C_, Ybf);
    gemm_bf_k<<<dim3(16, 130), 256, 0, stream>>>(Ybf, 512, Wf1,
        fc1b + i * HID_, nullptr, HB, 2048, 512, MODE_GELU, attn);
    gemm_bf_k<<<dim3(4, 130), 256, 0, stream>>>(HB, 2048, Wf2,
        fc2b + i * C_, X, nullptr, 512, 2048, MODE_RESID, attn);
  }
  final_k<<<B_, 256, 0, stream>>>(X, lnfg, lnfb, headW, headb, (float*)d_out);
}

// Round 6
// 3603.088 us; speedup vs baseline: 6.4935x; 1.0387x over previous
//
#include <hip/hip_runtime.h>
#include <cmath>
#include <cstdint>
#include <cstddef>

#define B_ 8
#define N_ 2048
#define NT 2049
#define NP 2080                /* padded tokens per batch */
#define C_ 512
#define H_ 8
#define HD_ 64
#define L_ 8
#define M_ 128
#define HID_ 2048
#define NC_ 2
#define BNT (B_*NT)            /* 16392 valid rows */
#define RP (B_*NP)             /* 16640 padded rows = 130*128 */
#define SCALE_ 0.125f
#define LN_EPS_ 1e-5f
#define FEAT_EPS_ 1e-6f

#define MODE_GELU  2
#define MODE_RESID 3

typedef unsigned short u16;
typedef unsigned short u16x8 __attribute__((ext_vector_type(8)));
typedef short frag __attribute__((ext_vector_type(8)));
typedef float f32x4 __attribute__((ext_vector_type(4)));

// ---------------- workspace layout ----------------
// floats
constexpr size_t F_X    = 0;                         // RP*512
constexpr size_t F_KVP  = F_X   + (size_t)RP*512;    // 4*64*8192
constexpr size_t F_KSP  = F_KVP + (size_t)4*64*8192;
constexpr size_t F_KV   = F_KSP + (size_t)4*64*128;
constexpr size_t F_KS   = F_KV  + (size_t)64*M_*HD_;
constexpr size_t F_QKVB = F_KS  + (size_t)64*M_;
constexpr size_t F_END  = F_QKVB + 1536;             // 11,183,616 floats
// u16 region
constexpr size_t S_BASE = 2 * F_END;
constexpr size_t S_Y    = S_BASE;                    // [RP][512]  Y; later CTX
constexpr size_t S_V    = S_Y  + (size_t)RP*512;     // [RP][512]  V; HB starts here
constexpr size_t S_KF   = S_V  + (size_t)RP*512;     // [RP][1024] KF
constexpr size_t S_QF   = S_KF + (size_t)RP*1024;    // [RP][1024] QF
constexpr size_t S_WQKV = S_QF + (size_t)RP*1024;    // 1536*512
constexpr size_t S_WO   = S_WQKV + (size_t)1536*512; // 512*512
constexpr size_t S_WF1  = S_WO   + (size_t)512*512;  // 2048*512
constexpr size_t S_WF2  = S_WF1  + (size_t)2048*512; // 512*2048
constexpr size_t S_PT   = S_WF2  + (size_t)512*2048; // 8*128*64
constexpr size_t S_END  = S_PT   + (size_t)8*128*64;
constexpr size_t WS_BYTES = S_END * 2;               // 153,393,152

// ---------------- helpers ----------------
__device__ __forceinline__ float wave_reduce(float v) {
#pragma unroll
  for (int off = 32; off > 0; off >>= 1) v += __shfl_down(v, off, 64);
  return v;
}
__device__ __forceinline__ float b2f(u16 u) {
  union { float f; uint32_t i; } v; v.i = ((uint32_t)u) << 16; return v.f;
}
__device__ __forceinline__ u16 f2b(float f) {
  union { float f; uint32_t i; } v; v.f = f;
  uint32_t r = v.i + 0x7FFF + ((v.i >> 16) & 1);
  return (u16)(r >> 16);
}
__device__ __forceinline__ void gstage(const u16* g, u16* lds_base, int lane) {
#if __has_builtin(__builtin_amdgcn_global_load_lds)
  __builtin_amdgcn_global_load_lds((const __attribute__((address_space(1))) void*)g,
      (__attribute__((address_space(3))) void*)lds_base, 16, 0, 0);
#else
  *(u16x8*)(lds_base + lane * 8) = *(const u16x8*)g;
#endif
}

// ---------------- embedding ----------------
__global__ __launch_bounds__(256) void embed_k(const int* __restrict__ ids,
    const float* __restrict__ tok, const float* __restrict__ cls,
    const float* __restrict__ pos, float* __restrict__ X) {
  int row = blockIdx.x;
  int b = row / NT, n = row - b * NT;
  int t = threadIdx.x;
  const float* src = (n == 0) ? cls : tok + (size_t)ids[b * N_ + n - 1] * C_;
  size_t rp = (size_t)b * NP + n;
  X[rp * C_ + t]       = src[t]       + pos[(size_t)n * C_ + t];
  X[rp * C_ + t + 256] = src[t + 256] + pos[(size_t)n * C_ + t + 256];
}

// ---------------- weight transpose + convert + PT + qkv bias (per layer) ----------------
__global__ __launch_bounds__(256) void wconv_k(
    const float* __restrict__ qW, const float* __restrict__ kW,
    const float* __restrict__ vW, const float* __restrict__ oW,
    const float* __restrict__ f1W, const float* __restrict__ f2W,
    const float* __restrict__ projL,
    const float* __restrict__ qb, const float* __restrict__ kb,
    const float* __restrict__ vb,
    u16* __restrict__ Wqkv, u16* __restrict__ Wo,
    u16* __restrict__ Wf1, u16* __restrict__ Wf2,
    u16* __restrict__ PT, float* __restrict__ QKVB) {
  __shared__ float tile[32][33];
  int bid = blockIdx.x, t = threadIdx.x;
  if (bid >= 3104) {            // qkv bias concat
    int i = (bid - 3104) * 256 + t;
    QKVB[i] = (i < 512) ? qb[i] : (i < 1024) ? kb[i - 512] : vb[i - 1024];
    return;
  }
  if (bid >= 3072) {            // PT[h][m][d] = proj[h][d][m]
    int base = (bid - 3072) * 2048 + t * 8;
#pragma unroll
    for (int j = 0; j < 8; ++j) {
      int idx = base + j;
      int h = idx >> 13, rem = idx & 8191, m = rem >> 6, d = rem & 63;
      PT[idx] = f2b(projL[(size_t)h * 8192 + d * 128 + m]);
    }
    return;
  }
  int ti = t >> 5, tj = t & 31;
  const float* src; u16* dst; int k0, n0, ldn, ldk, scol;
  if (bid < 768) {
    int tk = bid & 15, tn = bid >> 4;
    k0 = tk * 32; n0 = tn * 32;
    int sel = n0 >> 9; scol = n0 & 511;
    src = (sel == 0) ? qW : (sel == 1) ? kW : vW;
    ldn = 512; dst = Wqkv; ldk = 512;
  } else if (bid < 1024) {
    int b2 = bid - 768;
    int tk = b2 & 15, tn = b2 >> 4;
    k0 = tk * 32; n0 = tn * 32; scol = n0;
    src = oW; ldn = 512; dst = Wo; ldk = 512;
  } else if (bid < 2048) {
    int b2 = bid - 1024;
    int tk = b2 & 15, tn = b2 >> 4;
    k0 = tk * 32; n0 = tn * 32; scol = n0;
    src = f1W; ldn = 2048; dst = Wf1; ldk = 512;
  } else {
    int b2 = bid - 2048;
    int tk = b2 & 63, tn = b2 >> 6;
    k0 = tk * 32; n0 = tn * 32; scol = n0;
    src = f2W; ldn = 512; dst = Wf2; ldk = 2048;
  }
  const float* sp = src + (size_t)k0 * ldn + scol;
  u16* dp = dst + (size_t)n0 * ldk + k0;
#pragma unroll
  for (int p = 0; p < 4; ++p)
    tile[ti + p * 8][tj] = sp[(size_t)(ti + p * 8) * ldn + tj];
  __syncthreads();
#pragma unroll
  for (int p = 0; p < 4; ++p)
    dp[(size_t)(ti + p * 8) * ldk + tj] = f2b(tile[tj][ti + p * 8]);
}

// ---------------- LayerNorm -> bf16 ----------------
__global__ __launch_bounds__(256) void ln_bf_k(const float* __restrict__ X,
    const float* __restrict__ g, const float* __restrict__ b,
    u16* __restrict__ Y) {
  int w = threadIdx.x >> 6, lane = threadIdx.x & 63;
  int row = blockIdx.x * 4 + w;
  const float* xr = X + (size_t)row * C_;
  float v[8];
  *(float4*)&v[0] = *(const float4*)(xr + lane * 8);
  *(float4*)&v[4] = *(const float4*)(xr + lane * 8 + 4);
  float s = 0.f;
#pragma unroll
  for (int j = 0; j < 8; ++j) s += v[j];
  s = wave_reduce(s);
  float mu = __shfl(s, 0, 64) * (1.0f / C_);
  float sq = 0.f;
#pragma unroll
  for (int j = 0; j < 8; ++j) { float d = v[j] - mu; sq = fmaf(d, d, sq); }
  sq = wave_reduce(sq);
  float rs = rsqrtf(__shfl(sq, 0, 64) * (1.0f / C_) + LN_EPS_);
  float gv[8], bv[8];
  *(float4*)&gv[0] = *(const float4*)(g + lane * 8);
  *(float4*)&gv[4] = *(const float4*)(g + lane * 8 + 4);
  *(float4*)&bv[0] = *(const float4*)(b + lane * 8);
  *(float4*)&bv[4] = *(const float4*)(b + lane * 8 + 4);
  u16x8 o;
#pragma unroll
  for (int j = 0; j < 8; ++j) o[j] = f2b((v[j] - mu) * rs * gv[j] + bv[j]);
  *(u16x8*)(Y + (size_t)row * C_ + lane * 8) = o;
}

// ---------------- bf16 MFMA GEMM (o / fc1 / fc2): BK=64, XOR-swizzled LDS ----
__global__ __launch_bounds__(256) void gemm_bf_k(
    const u16* __restrict__ A, int lda,
    const u16* __restrict__ Wt,
    const float* __restrict__ bias,
    float* __restrict__ outF, u16* __restrict__ outB,
    int ldc, int Kdim, int mode) {
  __shared__ __align__(16) u16 As[128 * 64];
  __shared__ __align__(16) u16 Bs[128 * 64];
  const int t = threadIdx.x, w = t >> 6, l = t & 63;
  const int row0 = blockIdx.y * 128, col0 = blockIdx.x * 128;
  const int wm = w & 1, wn = w >> 1;
  const int lm = l & 15, lkb = l >> 4;
  const int lr = l >> 3, lc = l & 7;
  const int kch = (lc ^ lr) * 8;
  const u16* Ag = A  + (size_t)(row0 + lr) * lda  + kch;
  const u16* Bg = Wt + (size_t)(col0 + lr) * Kdim + kch;
  const int sx = lm & 7;
  f32x4 acc[4][4] = {};
  for (int k0 = 0; k0 < Kdim; k0 += 64) {
    __syncthreads();
#pragma unroll
    for (int j = 0; j < 4; ++j) {
      int c8 = w * 4 + j;
      gstage(Ag + (size_t)c8 * 8 * lda  + k0, &As[c8 * 512], l);
      gstage(Bg + (size_t)c8 * 8 * Kdim + k0, &Bs[c8 * 512], l);
    }
    __syncthreads();
#pragma unroll
    for (int ks = 0; ks < 2; ++ks) {
      frag af[4], bf4[4];
#pragma unroll
      for (int i = 0; i < 4; ++i)
        af[i] = *(const frag*)&As[(wm * 64 + i * 16 + lm) * 64 + (((ks * 4 + lkb) ^ sx) * 8)];
#pragma unroll
      for (int j = 0; j < 4; ++j)
        bf4[j] = *(const frag*)&Bs[(wn * 64 + j * 16 + lm) * 64 + (((ks * 4 + lkb) ^ sx) * 8)];
#pragma unroll
      for (int i = 0; i < 4; ++i)
#pragma unroll
        for (int j = 0; j < 4; ++j)
          acc[i][j] = __builtin_amdgcn_mfma_f32_16x16x32_bf16(af[i], bf4[j], acc[i][j], 0, 0, 0);
    }
  }
#pragma unroll
  for (int i = 0; i < 4; ++i) {
#pragma unroll
    for (int r = 0; r < 4; ++r) {
      int grow = row0 + wm * 64 + i * 16 + lkb * 4 + r;
      if (mode == MODE_RESID) {
        float* orow = outF + (size_t)grow * ldc + col0;
#pragma unroll
        for (int j = 0; j < 4; ++j) {
          int gc = wn * 64 + j * 16 + lm;
          orow[gc] += acc[i][j][r] + bias[col0 + gc];
        }
      } else { // MODE_GELU (fast sigmoid form)
        u16* orow = outB + (size_t)grow * ldc + col0;
#pragma unroll
        for (int j = 0; j < 4; ++j) {
          int gc = wn * 64 + j * 16 + lm;
          float v = acc[i][j][r] + bias[col0 + gc];
          float u = v * (1.5957691216f + 0.0713548162f * v * v);
          v = v / (1.f + __expf(-u));
          orow[gc] = f2b(v);
        }
      }
    }
  }
}

// ---------------- fused QKV GEMM + feature map ----------------
// grid (12, 130). col-blocks 0..3: q-heads, 4..7: k-heads, 8..11: v.
// q/k blocks: main GEMM -> acc to LDS (swizzled) -> ||x||^2 -> MFMA vs PT[h]
// -> exp epilogue -> QF/KF. v blocks: masked bf16 V to compact [RP][512].
__global__ __launch_bounds__(256) void gemmqkv_k(
    const u16* __restrict__ A,
    const u16* __restrict__ Wt,          // Wqkv [1536][512]
    const float* __restrict__ bias,      // [1536]
    u16* __restrict__ Vout,              // [RP][512]
    u16* __restrict__ QF, u16* __restrict__ KF,   // [RP][1024]
    const u16* __restrict__ PT,          // [8][128][64]
    const int* __restrict__ attn) {
  __shared__ __align__(16) u16 As[128 * 64];   // later: qtile head0
  __shared__ __align__(16) u16 Bs[128 * 64];   // later: qtile head1
  __shared__ __align__(16) u16 ptb[128 * 64];  // PT[h] staged, swizzled
  __shared__ float sxe[128][2];
  const int t = threadIdx.x, w = t >> 6, l = t & 63;
  const int cx = blockIdx.x;
  const int row0 = blockIdx.y * 128, col0 = cx * 128;
  const int wm = w & 1, wn = w >> 1;
  const int lm = l & 15, lkb = l >> 4;
  const int lr = l >> 3, lc = l & 7;
  const int kch = (lc ^ lr) * 8;
  const u16* Ag = A  + (size_t)(row0 + lr) * 512 + kch;
  const u16* Bg = Wt + (size_t)(col0 + lr) * 512 + kch;
  const int sx = lm & 7;
  f32x4 acc[4][4] = {};
  for (int k0 = 0; k0 < 512; k0 += 64) {
    __syncthreads();
#pragma unroll
    for (int j = 0; j < 4; ++j) {
      int c8 = w * 4 + j;
      gstage(Ag + (size_t)c8 * 8 * 512 + k0, &As[c8 * 512], l);
      gstage(Bg + (size_t)c8 * 8 * 512 + k0, &Bs[c8 * 512], l);
    }
    __syncthreads();
#pragma unroll
    for (int ks = 0; ks < 2; ++ks) {
      frag af[4], bf4[4];
#pragma unroll
      for (int i = 0; i < 4; ++i)
        af[i] = *(const frag*)&As[(wm * 64 + i * 16 + lm) * 64 + (((ks * 4 + lkb) ^ sx) * 8)];
#pragma unroll
      for (int j = 0; j < 4; ++j)
        bf4[j] = *(const frag*)&Bs[(wn * 64 + j * 16 + lm) * 64 + (((ks * 4 + lkb) ^ sx) * 8)];
#pragma unroll
      for (int i = 0; i < 4; ++i)
#pragma unroll
        for (int j = 0; j < 4; ++j)
          acc[i][j] = __builtin_amdgcn_mfma_f32_16x16x32_bf16(af[i], bf4[j], acc[i][j], 0, 0, 0);
    }
  }
  // ---- V path ----
  if (cx >= 8) {
    int c0v = col0 - 1024;
#pragma unroll
    for (int i = 0; i < 4; ++i) {
#pragma unroll
      for (int r = 0; r < 4; ++r) {
        int grow = row0 + wm * 64 + i * 16 + lkb * 4 + r;
        int bb = grow / NP, nn = grow - bb * NP;
        float mrow = (nn == 0) ? 1.f : ((nn < NT) ? (float)attn[bb * N_ + nn - 1] : 0.f);
        u16* orow = Vout + (size_t)grow * 512 + c0v;
#pragma unroll
        for (int j = 0; j < 4; ++j) {
          int gc = wn * 64 + j * 16 + lm;
          orow[gc] = f2b((acc[i][j][r] + bias[col0 + gc]) * mrow);
        }
      }
    }
    return;
  }
  // ---- Q/K path: write scaled/masked tile to LDS (swizzled, per-head) ----
  const bool isq = (cx < 4);
  const int hbase = (isq ? cx : cx - 4) * 2;
  __syncthreads();            // all waves done reading As/Bs
  {
    u16* qt = wn ? Bs : As;
#pragma unroll
    for (int i = 0; i < 4; ++i) {
#pragma unroll
      for (int r = 0; r < 4; ++r) {
        int rl = wm * 64 + i * 16 + lkb * 4 + r;
        float mrow;
        if (isq) mrow = SCALE_;
        else {
          int grow = row0 + rl;
          int bb = grow / NP, nn = grow - bb * NP;
          mrow = (nn == 0) ? 1.f : ((nn < NT) ? (float)attn[bb * N_ + nn - 1] : 0.f);
        }
#pragma unroll
        for (int j = 0; j < 4; ++j) {
          int gcc = j * 16 + lm;
          float v = (acc[i][j][r] + bias[col0 + wn * 64 + gcc]) * mrow;
          qt[rl * 64 + (((gcc >> 3) ^ (rl & 7)) * 8) + (gcc & 7)] = f2b(v);
        }
      }
    }
  }
  // stage PT for head hbase+0 (independent of qtile)
  {
    const u16* Pg = PT + (size_t)hbase * 8192 + (size_t)lr * 64 + kch;
#pragma unroll
    for (int q = 0; q < 4; ++q) {
      int c8 = w * 4 + q;
      gstage(Pg + (size_t)c8 * 8 * 64, &ptb[c8 * 512], l);
    }
  }
  __syncthreads();
  // ---- 0.5*||x||^2 per (row, head) ----
  {
    int rowi = t >> 1, hf = t & 1;
    const u16* qq = hf ? Bs : As;
    float s = 0.f;
#pragma unroll
    for (int c = 0; c < 8; ++c) {
      const u16* p = &qq[rowi * 64 + ((c ^ (rowi & 7)) * 8)];
#pragma unroll
      for (int e = 0; e < 8; ++e) { float a = b2f(p[e]); s = fmaf(a, a, s); }
    }
    sxe[rowi][hf] = 0.5f * s;
  }
  __syncthreads();
  // ---- feature MFMA per head ----
  u16* OF = isq ? QF : KF;
#pragma unroll
  for (int hp = 0; hp < 2; ++hp) {
    if (hp == 1) {
      __syncthreads();
      const u16* Pg = PT + (size_t)(hbase + 1) * 8192 + (size_t)lr * 64 + kch;
#pragma unroll
      for (int q = 0; q < 4; ++q) {
        int c8 = w * 4 + q;
        gstage(Pg + (size_t)c8 * 8 * 64, &ptb[c8 * 512], l);
      }
      __syncthreads();
    }
    const u16* qt = hp ? Bs : As;
    f32x4 a2[2][8] = {};
#pragma unroll
    for (int ks = 0; ks < 2; ++ks) {
      frag af2[2], bf2[8];
#pragma unroll
      for (int i = 0; i < 2; ++i)
        af2[i] = *(const frag*)&qt[(w * 32 + i * 16 + lm) * 64 + (((ks * 4 + lkb) ^ sx) * 8)];
#pragma unroll
      for (int j = 0; j < 8; ++j)
        bf2[j] = *(const frag*)&ptb[(j * 16 + lm) * 64 + (((ks * 4 + lkb) ^ sx) * 8)];
#pragma unroll
      for (int i = 0; i < 2; ++i)
#pragma unroll
        for (int j = 0; j < 8; ++j)
          a2[i][j] = __builtin_amdgcn_mfma_f32_16x16x32_bf16(af2[i], bf2[j], a2[i][j], 0, 0, 0);
    }
    int hg = hbase + hp;
#pragma unroll
    for (int i = 0; i < 2; ++i) {
#pragma unroll
      for (int r = 0; r < 4; ++r) {
        int R = w * 32 + i * 16 + lkb * 4 + r;
        int grow = row0 + R;
        int bb = grow / NP, nn = grow - bb * NP;
        bool valid = nn < NT;
        float xs = sxe[R][hp];
        u16* orow = OF + (size_t)grow * 1024 + (size_t)hg * 128;
#pragma unroll
        for (int j = 0; j < 8; ++j) {
          int m = j * 16 + lm;
          float v = valid ? (__expf(a2[i][j][r] - xs) + FEAT_EPS_) : 0.f;
          orow[m] = f2b(v);
        }
      }
    }
  }
}

// ---------------- kv partial (pure accumulation, fp32) ----------------
__global__ __launch_bounds__(256) void kvpart_k(const u16* __restrict__ KF,
    const u16* __restrict__ Vb, float* __restrict__ KVP,
    float* __restrict__ KSP) {
  int ci = blockIdx.x, bh = blockIdx.y;
  int b = bh >> 3, h = bh & 7;
  size_t rb0 = (size_t)b * NP + ci * 520;
  __shared__ __align__(16) float kfs[8 * 132];
  __shared__ __align__(16) float vsm[8 * 68];
  int t = threadIdx.x;
  const int d0 = (t & 7) * 8, m0 = (t >> 3) * 4;
  float acc[4][8] = {};
  float ks[4] = {};
  for (int tile = 0; tile < 65; ++tile) {
    size_t rb = rb0 + tile * 8;
#pragma unroll
    for (int p = 0; p < 4; ++p) {
      int e = p * 256 + t; int m = e & 127; int tok = e >> 7;
      kfs[tok * 132 + m] = b2f(KF[(rb + tok) * 1024 + h * 128 + m]);
    }
#pragma unroll
    for (int p = 0; p < 2; ++p) {
      int e = p * 256 + t; int d = e & 63; int tok = e >> 6;
      vsm[tok * 68 + d] = b2f(Vb[(rb + tok) * 512 + h * 64 + d]);
    }
    __syncthreads();
#pragma unroll
    for (int tok = 0; tok < 8; ++tok) {
      float kq[4], va[8];
      *(float4*)&kq[0] = *(const float4*)&kfs[tok * 132 + m0];
      *(float4*)&va[0] = *(const float4*)&vsm[tok * 68 + d0];
      *(float4*)&va[4] = *(const float4*)&vsm[tok * 68 + d0 + 4];
#pragma unroll
      for (int mi = 0; mi < 4; ++mi)
#pragma unroll
        for (int di = 0; di < 8; ++di)
          acc[mi][di] = fmaf(kq[mi], va[di], acc[mi][di]);
      if ((t & 7) == 0) { ks[0] += kq[0]; ks[1] += kq[1]; ks[2] += kq[2]; ks[3] += kq[3]; }
    }
    __syncthreads();
  }
  size_t base = ((size_t)ci * 64 + bh) * 8192;
#pragma unroll
  for (int mi = 0; mi < 4; ++mi)
#pragma unroll
    for (int di = 0; di < 8; ++di)
      KVP[base + (size_t)(m0 + mi) * 64 + d0 + di] = acc[mi][di];
  if ((t & 7) == 0) {
#pragma unroll
    for (int mi = 0; mi < 4; ++mi)
      KSP[((size_t)ci * 64 + bh) * 128 + m0 + mi] = ks[mi];
  }
}

__global__ __launch_bounds__(256) void kvred_k(const float* __restrict__ KVP,
    const float* __restrict__ KSP, float* __restrict__ KV,
    float* __restrict__ KSUM) {
  int bh = blockIdx.x, t = threadIdx.x;
#pragma unroll
  for (int p = 0; p < 32; ++p) {
    int e = p * 256 + t;
    float s = 0.f;
#pragma unroll
    for (int ci = 0; ci < 4; ++ci) s += KVP[((size_t)ci * 64 + bh) * 8192 + e];
    KV[(size_t)bh * 8192 + e] = s;
  }
  if (t < 128) {
    float s = 0.f;
#pragma unroll
    for (int ci = 0; ci < 4; ++ci) s += KSP[((size_t)ci * 64 + bh) * 128 + t];
    KSUM[(size_t)bh * 128 + t] = s;
  }
}

// ---------------- ctx: (qf @ kv) / max(qf . ksum, 1e-6) ----------------
__global__ __launch_bounds__(256) void ctx_k(const u16* __restrict__ QF,
    const float* __restrict__ KVg, const float* __restrict__ KSUM,
    u16* __restrict__ CTXo) {
  __shared__ float qfs[128 * 36];
  __shared__ float kvs[128 * 68];
  __shared__ float ksums[128];
  __shared__ float dls[32];
  __shared__ float dpart[8 * 32];
  int t = threadIdx.x;
  int bh = blockIdx.y; int b = bh >> 3, h = bh & 7;
  int n0 = blockIdx.x * 32;
  size_t rbase = (size_t)b * NP + n0;
#pragma unroll
  for (int p = 0; p < 16; ++p) {
    int e = p * 256 + t; int m = e & 127; int tok = e >> 7;
    qfs[m * 36 + tok] = b2f(QF[(rbase + tok) * 1024 + h * 128 + m]);
  }
#pragma unroll
  for (int p = 0; p < 32; ++p) {
    int e = p * 256 + t;
    kvs[(e >> 6) * 68 + (e & 63)] = KVg[(size_t)bh * 8192 + e];
  }
  if (t < 128) ksums[t] = KSUM[bh * 128 + t];
  __syncthreads();
  {
    int j = t & 31, pp = t >> 5;
    float s = 0.f;
#pragma unroll
    for (int mi = 0; mi < 16; ++mi) {
      int m = pp * 16 + mi;
      s = fmaf(qfs[m * 36 + j], ksums[m], s);
    }
    dpart[pp * 32 + j] = s;
  }
  __syncthreads();
  if (t < 32) {
    float den = 0.f;
#pragma unroll
    for (int pp = 0; pp < 8; ++pp) den += dpart[pp * 32 + t];
    dls[t] = 1.f / fmaxf(den, 1e-6f);
  }
  __syncthreads();
  {
    const int d0 = (t & 15) * 4, tok0 = (t >> 4) * 2;
    float acc[2][4] = {};
#pragma unroll 16
    for (int m = 0; m < 128; ++m) {
      float q0 = qfs[m * 36 + tok0];
      float q1 = qfs[m * 36 + tok0 + 1];
      float4 kv4 = *(const float4*)&kvs[m * 68 + d0];
      acc[0][0] = fmaf(q0, kv4.x, acc[0][0]); acc[0][1] = fmaf(q0, kv4.y, acc[0][1]);
      acc[0][2] = fmaf(q0, kv4.z, acc[0][2]); acc[0][3] = fmaf(q0, kv4.w, acc[0][3]);
      acc[1][0] = fmaf(q1, kv4.x, acc[1][0]); acc[1][1] = fmaf(q1, kv4.y, acc[1][1]);
      acc[1][2] = fmaf(q1, kv4.z, acc[1][2]); acc[1][3] = fmaf(q1, kv4.w, acc[1][3]);
    }
#pragma unroll
    for (int r = 0; r < 2; ++r) {
      int n = n0 + tok0 + r;
      if (n >= NT) continue;
      float rd = dls[tok0 + r];
      u16* o = CTXo + (rbase + tok0 + r) * C_ + h * HD_ + d0;
#pragma unroll
      for (int c = 0; c < 4; ++c) o[c] = f2b(acc[r][c] * rd);
    }
  }
}

// ---------------- final: LN(x[b,0]) @ headW + headb ----------------
__global__ __launch_bounds__(256) void final_k(const float* __restrict__ X,
    const float* __restrict__ g, const float* __restrict__ beta,
    const float* __restrict__ hW, const float* __restrict__ hb,
    float* __restrict__ out) {
  int b = blockIdx.x, t = threadIdx.x;
  const float* xr = X + (size_t)b * NP * C_;
  float v0 = xr[t], v1 = xr[t + 256];
  __shared__ float red[4][4];
  float s = wave_reduce(v0 + v1);
  if ((t & 63) == 0) red[0][t >> 6] = s;
  __syncthreads();
  float mu = (red[0][0] + red[0][1] + red[0][2] + red[0][3]) * (1.0f / C_);
  float d0 = v0 - mu, d1 = v1 - mu;
  float s2 = wave_reduce(d0 * d0 + d1 * d1);
  if ((t & 63) == 0) red[1][t >> 6] = s2;
  __syncthreads();
  float var = (red[1][0] + red[1][1] + red[1][2] + red[1][3]) * (1.0f / C_);
  float rs = rsqrtf(var + LN_EPS_);
  float n0 = d0 * rs * g[t] + beta[t];
  float n1 = d1 * rs * g[t + 256] + beta[t + 256];
  float p0 = n0 * hW[t * NC_]     + n1 * hW[(t + 256) * NC_];
  float p1 = n0 * hW[t * NC_ + 1] + n1 * hW[(t + 256) * NC_ + 1];
  float t0 = wave_reduce(p0);
  float t1 = wave_reduce(p1);
  if ((t & 63) == 0) { red[2][t >> 6] = t0; red[3][t >> 6] = t1; }
  __syncthreads();
  if (t == 0) {
    out[b * NC_]     = red[2][0] + red[2][1] + red[2][2] + red[2][3] + hb[0];
    out[b * NC_ + 1] = red[3][0] + red[3][1] + red[3][2] + red[3][3] + hb[1];
  }
}

// ---------------- launch ----------------
extern "C" void kernel_launch(void* const* d_in, const int* in_sizes, int n_in,
                              void* d_out, int out_size, void* d_ws, size_t ws_size,
                              hipStream_t stream) {
  if (ws_size < WS_BYTES) return;  // diagnostic guard
  const int*   ids   = (const int*)d_in[0];
  const int*   attn  = (const int*)d_in[1];
  const float* tok   = (const float*)d_in[2];
  const float* cls   = (const float*)d_in[3];
  const float* pos   = (const float*)d_in[4];
  const float* ln1g  = (const float*)d_in[5];
  const float* ln1b  = (const float*)d_in[6];
  const float* qW    = (const float*)d_in[7];
  const float* qb    = (const float*)d_in[8];
  const float* kW    = (const float*)d_in[9];
  const float* kb    = (const float*)d_in[10];
  const float* vW    = (const float*)d_in[11];
  const float* vb    = (const float*)d_in[12];
  const float* oW    = (const float*)d_in[13];
  const float* ob    = (const float*)d_in[14];
  const float* proj  = (const float*)d_in[15];
  const float* ln2g  = (const float*)d_in[16];
  const float* ln2b  = (const float*)d_in[17];
  const float* fc1W  = (const float*)d_in[18];
  const float* fc1b  = (const float*)d_in[19];
  const float* fc2W  = (const float*)d_in[20];
  const float* fc2b  = (const float*)d_in[21];
  const float* lnfg  = (const float*)d_in[22];
  const float* lnfb  = (const float*)d_in[23];
  const float* headW = (const float*)d_in[24];
  const float* headb = (const float*)d_in[25];

  float* ws  = (float*)d_ws;
  u16*   wsu = (u16*)d_ws;
  float* X    = ws + F_X;
  float* KVP  = ws + F_KVP;
  float* KSP  = ws + F_KSP;
  float* KV   = ws + F_KV;
  float* KSUM = ws + F_KS;
  float* QKVB = ws + F_QKVB;
  u16* Ybf  = wsu + S_Y;    // [RP][512]; CTX aliases (temporally disjoint)
  u16* CTXb = wsu + S_Y;
  u16* Vb   = wsu + S_V;    // [RP][512]; HB[RP][2048] starts here (V+KF+QF/2 dead by FFN)
  u16* HB   = wsu + S_V;
  u16* KFb  = wsu + S_KF;   // [RP][1024]
  u16* QFb  = wsu + S_QF;   // [RP][1024]
  u16* Wqkv = wsu + S_WQKV;
  u16* Wo   = wsu + S_WO;
  u16* Wf1  = wsu + S_WF1;
  u16* Wf2  = wsu + S_WF2;
  u16* PT   = wsu + S_PT;

  embed_k<<<BNT, 256, 0, stream>>>(ids, tok, cls, pos, X);
  for (int i = 0; i < L_; ++i) {
    wconv_k<<<3110, 256, 0, stream>>>(qW + (size_t)i * C_ * C_, kW + (size_t)i * C_ * C_,
        vW + (size_t)i * C_ * C_, oW + (size_t)i * C_ * C_,
        fc1W + (size_t)i * C_ * HID_, fc2W + (size_t)i * HID_ * C_,
        proj + (size_t)i * H_ * HD_ * M_,
        qb + i * C_, kb + i * C_, vb + i * C_,
        Wqkv, Wo, Wf1, Wf2, PT, QKVB);
    ln_bf_k<<<RP / 4, 256, 0, stream>>>(X, ln1g + i * C_, ln1b + i * C_, Ybf);
    gemmqkv_k<<<dim3(12, 130), 256, 0, stream>>>(Ybf, Wqkv, QKVB,
        Vb, QFb, KFb, PT, attn);
    kvpart_k<<<dim3(4, 64), 256, 0, stream>>>(KFb, Vb, KVP, KSP);
    kvred_k<<<64, 256, 0, stream>>>(KVP, KSP, KV, KSUM);
    ctx_k<<<dim3(65, 64), 256, 0, stream>>>(QFb, KV, KSUM, CTXb);
    gemm_bf_k<<<dim3(4, 130), 256, 0, stream>>>(CTXb, 512, Wo, ob + i * C_,
        X, nullptr, 512, 512, MODE_RESID);
    ln_bf_k<<<RP / 4, 256, 0, stream>>>(X, ln2g + i * C_, ln2b + i * C_, Ybf);
    gemm_bf_k<<<dim3(16, 130), 256, 0, stream>>>(Ybf, 512, Wf1,
        fc1b + i * HID_, nullptr, HB, 2048, 512, MODE_GELU);
    gemm_bf_k<<<dim3(4, 130), 256, 0, stream>>>(HB, 2048, Wf2,
        fc2b + i * C_, X, nullptr, 512, 2048, MODE_RESID);
  }
  final_k<<<B_, 256, 0, stream>>>(X, lnfg, lnfb, headW, headb, (float*)d_out);
}